// Round 1
// baseline (1004.290 us; speedup 1.0000x reference)
//
#include <hip/hip_runtime.h>

#define N_NODES 50000
#define N_EDGES 1600000
#define HALF 128
#define NEG_SLOPE 0.2f

// ---------------- CSR build ----------------

__global__ __launch_bounds__(256) void k_init_deg(int* cf, int* cb) {
  int i = blockIdx.x * 256 + threadIdx.x;
  if (i < N_NODES) { cf[i] = 1; cb[i] = 1; }  // self loop counts as 1
}

__global__ __launch_bounds__(256) void k_degree(const int* __restrict__ ei, int* cf, int* cb) {
  int e = blockIdx.x * 256 + threadIdx.x;
  if (e < N_EDGES) {
    int s = ei[e];
    int d = ei[N_EDGES + e];
    atomicAdd(&cf[d], 1);  // fwd groups by dst
    atomicAdd(&cb[s], 1);  // bwd groups by src
  }
}

__global__ __launch_bounds__(256) void k_scan1(const int* __restrict__ df, const int* __restrict__ db,
                                               int* rpf, int* rpb, int* bsum) {
  int dir = blockIdx.y;
  const int* deg = dir ? db : df;
  int* rp = dir ? rpb : rpf;
  __shared__ int s[256];
  int t = threadIdx.x;
  int i = blockIdx.x * 256 + t;
  int v = (i < N_NODES) ? deg[i] : 0;
  s[t] = v;
  __syncthreads();
  for (int off = 1; off < 256; off <<= 1) {
    int u = (t >= off) ? s[t - off] : 0;
    __syncthreads();
    s[t] += u;
    __syncthreads();
  }
  if (i < N_NODES) rp[i + 1] = s[t];
  if (t == 255) bsum[dir * 256 + blockIdx.x] = s[255];
}

__global__ __launch_bounds__(256) void k_scan2(const int* __restrict__ bsum, int* bsumex) {
  int dir = blockIdx.y;
  const int NB = (N_NODES + 255) / 256;
  __shared__ int s[256];
  int t = threadIdx.x;
  int v = (t < NB) ? bsum[dir * 256 + t] : 0;
  s[t] = v;
  __syncthreads();
  for (int off = 1; off < 256; off <<= 1) {
    int u = (t >= off) ? s[t - off] : 0;
    __syncthreads();
    s[t] += u;
    __syncthreads();
  }
  bsumex[dir * 256 + t] = s[t] - v;  // exclusive
}

__global__ __launch_bounds__(256) void k_scan3(int* rpf, int* rpb, const int* __restrict__ bsumex) {
  int dir = blockIdx.y;
  int* rp = dir ? rpb : rpf;
  int t = threadIdx.x;
  int i = blockIdx.x * 256 + t;
  if (i < N_NODES) rp[i + 1] += bsumex[dir * 256 + blockIdx.x];
  if (i == 0) rp[0] = 0;
}

__global__ __launch_bounds__(256) void k_selfloop(const int* __restrict__ rpf, const int* __restrict__ rpb,
                                                  int* adjf, int* adjb, int* cf, int* cb) {
  int dir = blockIdx.y;
  const int* rp = dir ? rpb : rpf;
  int* adj = dir ? adjb : adjf;
  int* cur = dir ? cb : cf;
  int i = blockIdx.x * 256 + threadIdx.x;
  if (i < N_NODES) {
    int c = rp[i];
    adj[c] = i;      // self loop first
    cur[i] = c + 1;  // cursor for edge scatter
  }
}

__global__ __launch_bounds__(256) void k_scatter(const int* __restrict__ ei, int* cf, int* cb,
                                                 int* adjf, int* adjb) {
  int e = blockIdx.x * 256 + threadIdx.x;
  if (e < N_EDGES) {
    int s = ei[e];
    int d = ei[N_EDGES + e];
    int p = atomicAdd(&cf[d], 1);
    adjf[p] = s;  // fwd: node d receives message from s
    int q = atomicAdd(&cb[s], 1);
    adjb[q] = d;  // bwd: node s receives message from d
  }
}

// ---------------- GEMM (M x 256) @ (256 x 256) fp32 tiled ----------------
// mode 0: B = [W_f | W_b] (each ldb=128), plain output
// mode 1: B = W_fuse (ldb=256), epilogue = +bias, BN(eval), ReLU

__global__ __launch_bounds__(256) void k_gemm(
    const float* __restrict__ A, int M,
    const float* __restrict__ B0, const float* __restrict__ B1,
    float* __restrict__ Cdst, int mode,
    const float* __restrict__ bias, const float* __restrict__ gamma,
    const float* __restrict__ beta, const float* __restrict__ mean,
    const float* __restrict__ var)
{
  const int tid = threadIdx.x;
  const int m0 = blockIdx.x * 64;
  const int col0 = blockIdx.y * 64;
  const float* B; int bld, bc0;
  if (mode == 0) {
    bld = 128;
    if (col0 < 128) { B = B0; bc0 = col0; } else { B = B1; bc0 = col0 - 128; }
  } else {
    B = B0; bld = 256; bc0 = col0;
  }

  __shared__ float As[16][64];
  __shared__ float Bs[16][64];

  const int mA = tid >> 2, kq = (tid & 3) * 4;
  const int rowA = m0 + mA;
  const float* aptr = A + (size_t)rowA * 256 + kq;
  const int kB = tid >> 4, cB = (tid & 15) * 4;
  const float* bptr = B + (size_t)kB * bld + bc0 + cB;

  const int ty = tid >> 4, tx = tid & 15;
  const int my = ty * 4, cx = tx * 4;
  float acc[4][4];
#pragma unroll
  for (int i = 0; i < 4; ++i)
#pragma unroll
    for (int j = 0; j < 4; ++j) acc[i][j] = 0.f;

  for (int k0 = 0; k0 < 256; k0 += 16) {
    float4 av = make_float4(0.f, 0.f, 0.f, 0.f);
    if (rowA < M) av = *(const float4*)(aptr + k0);
    float4 bv = *(const float4*)(bptr + (size_t)k0 * bld);
    __syncthreads();
    As[kq + 0][mA] = av.x; As[kq + 1][mA] = av.y;
    As[kq + 2][mA] = av.z; As[kq + 3][mA] = av.w;
    *(float4*)&Bs[kB][cB] = bv;
    __syncthreads();
#pragma unroll
    for (int k = 0; k < 16; ++k) {
      float4 a = *(const float4*)&As[k][my];
      float4 b = *(const float4*)&Bs[k][cx];
      acc[0][0] = fmaf(a.x, b.x, acc[0][0]); acc[0][1] = fmaf(a.x, b.y, acc[0][1]);
      acc[0][2] = fmaf(a.x, b.z, acc[0][2]); acc[0][3] = fmaf(a.x, b.w, acc[0][3]);
      acc[1][0] = fmaf(a.y, b.x, acc[1][0]); acc[1][1] = fmaf(a.y, b.y, acc[1][1]);
      acc[1][2] = fmaf(a.y, b.z, acc[1][2]); acc[1][3] = fmaf(a.y, b.w, acc[1][3]);
      acc[2][0] = fmaf(a.z, b.x, acc[2][0]); acc[2][1] = fmaf(a.z, b.y, acc[2][1]);
      acc[2][2] = fmaf(a.z, b.z, acc[2][2]); acc[2][3] = fmaf(a.z, b.w, acc[2][3]);
      acc[3][0] = fmaf(a.w, b.x, acc[3][0]); acc[3][1] = fmaf(a.w, b.y, acc[3][1]);
      acc[3][2] = fmaf(a.w, b.z, acc[3][2]); acc[3][3] = fmaf(a.w, b.w, acc[3][3]);
    }
  }

#pragma unroll
  for (int i = 0; i < 4; ++i) {
    int row = m0 + my + i;
    if (row < M) {
#pragma unroll
      for (int j = 0; j < 4; ++j) {
        int col = col0 + cx + j;
        float v = acc[i][j];
        if (mode == 1) {
          v += bias[col];
          v = (v - mean[col]) * rsqrtf(var[col] + 1e-5f) * gamma[col] + beta[col];
          v = fmaxf(v, 0.f);
        }
        Cdst[(size_t)row * 256 + col] = v;
      }
    }
  }
}

// ---------------- per-node attention score dots ----------------

__global__ __launch_bounds__(64) void k_scores(
    const float* __restrict__ XL,
    const float* __restrict__ asf, const float* __restrict__ adf,
    const float* __restrict__ asb, const float* __restrict__ adb,
    float* __restrict__ ALf, float* __restrict__ ARf,
    float* __restrict__ ALb, float* __restrict__ ARb)
{
  int n = blockIdx.x;
  int lane = threadIdx.x;
  int hh = lane >> 5;  // 0/1
  int c = lane & 31;
  const float* row = XL + (size_t)n * 256;
  float v0 = row[lane];        // fwd head hh
  float v1 = row[64 + lane];   // fwd head 2+hh
  float v2 = row[128 + lane];  // bwd head hh
  float v3 = row[192 + lane];  // bwd head 2+hh
  float s0 = v0 * asf[hh * 32 + c],       d0 = v0 * adf[hh * 32 + c];
  float s1 = v1 * asf[(2 + hh) * 32 + c], d1 = v1 * adf[(2 + hh) * 32 + c];
  float s2 = v2 * asb[hh * 32 + c],       d2 = v2 * adb[hh * 32 + c];
  float s3 = v3 * asb[(2 + hh) * 32 + c], d3 = v3 * adb[(2 + hh) * 32 + c];
#pragma unroll
  for (int off = 16; off > 0; off >>= 1) {
    s0 += __shfl_xor(s0, off, 32); d0 += __shfl_xor(d0, off, 32);
    s1 += __shfl_xor(s1, off, 32); d1 += __shfl_xor(d1, off, 32);
    s2 += __shfl_xor(s2, off, 32); d2 += __shfl_xor(d2, off, 32);
    s3 += __shfl_xor(s3, off, 32); d3 += __shfl_xor(d3, off, 32);
  }
  if (c == 0) {
    ALf[n * 4 + hh] = s0;     ARf[n * 4 + hh] = d0;
    ALf[n * 4 + 2 + hh] = s1; ARf[n * 4 + 2 + hh] = d1;
    ALb[n * 4 + hh] = s2;     ARb[n * 4 + hh] = d2;
    ALb[n * 4 + 2 + hh] = s3; ARb[n * 4 + 2 + hh] = d3;
  }
}

// ---------------- fused softmax + aggregation (one wave per node,dir) ----------------
// out[n] = (sum_e w_e * xl[nbr_e]) / (sum_e w_e + 1e-16) + bias
// w_e = exp(leaky_relu(AL[nbr] + AR[n]))  -- softmax shift-invariance lets us skip segment_max

__global__ __launch_bounds__(64) void k_agg(
    const float* __restrict__ XL,
    const int* __restrict__ rpf, const int* __restrict__ adjf,
    const int* __restrict__ rpb, const int* __restrict__ adjb,
    const float* __restrict__ ALf, const float* __restrict__ ARf,
    const float* __restrict__ ALb, const float* __restrict__ ARb,
    const float* __restrict__ bf, const float* __restrict__ bb,
    float* __restrict__ H)
{
  const int n = blockIdx.x;
  const int dir = blockIdx.y;
  const int* rp  = dir ? rpb : rpf;
  const int* adj = dir ? adjb : adjf;
  const float* AL = dir ? ALb : ALf;
  const float* AR = dir ? ARb : ARf;
  const float* bias = dir ? bb : bf;
  const int lane = threadIdx.x;
  const int ch = lane * 2;       // 2 channels per lane (128 total)
  const int h = lane >> 4;       // head of both channels
  const float arn = AR[n * 4 + h];
  const int beg = rp[n], end = rp[n + 1];
  float accx = 0.f, accy = 0.f, den = 0.f;
  const float* xbase = XL + dir * HALF + ch;
  for (int j = beg; j < end; ++j) {
    int nb = adj[j];
    float e = AL[nb * 4 + h] + arn;
    e = (e > 0.f) ? e : NEG_SLOPE * e;
    float w = __expf(e);
    den += w;
    float2 v = *(const float2*)(xbase + (size_t)nb * 256);
    accx = fmaf(w, v.x, accx);
    accy = fmaf(w, v.y, accy);
  }
  float inv = 1.f / (den + 1e-16f);
  float* outp = H + (size_t)n * 256 + dir * HALF + ch;
  float2 r;
  r.x = accx * inv + bias[ch];
  r.y = accy * inv + bias[ch + 1];
  *(float2*)outp = r;
}

// ---------------- launch ----------------

extern "C" void kernel_launch(void* const* d_in, const int* in_sizes, int n_in,
                              void* d_out, int out_size, void* d_ws, size_t ws_size,
                              hipStream_t stream) {
  const float* x    = (const float*)d_in[0];
  const int*   ei   = (const int*)d_in[1];
  const float* W_f  = (const float*)d_in[2];
  const float* asf  = (const float*)d_in[3];
  const float* adf  = (const float*)d_in[4];
  const float* b_f  = (const float*)d_in[5];
  const float* W_b  = (const float*)d_in[6];
  const float* asb  = (const float*)d_in[7];
  const float* adb  = (const float*)d_in[8];
  const float* b_b  = (const float*)d_in[9];
  const float* W_fu = (const float*)d_in[10];
  const float* b_fu = (const float*)d_in[11];
  const float* gam  = (const float*)d_in[12];
  const float* bet  = (const float*)d_in[13];
  const float* mean = (const float*)d_in[14];
  const float* var  = (const float*)d_in[15];
  float* out = (float*)d_out;

  char* base = (char*)d_ws;
  size_t off = 0;
  auto alloc = [&](size_t bytes) {
    void* p = base + off;
    off = (off + bytes + 255) & ~(size_t)255;
    return p;
  };
  float* XL   = (float*)alloc((size_t)N_NODES * 256 * 4);
  float* H    = (float*)alloc((size_t)N_NODES * 256 * 4);
  float* ALf  = (float*)alloc((size_t)N_NODES * 4 * 4);
  float* ARf  = (float*)alloc((size_t)N_NODES * 4 * 4);
  float* ALb  = (float*)alloc((size_t)N_NODES * 4 * 4);
  float* ARb  = (float*)alloc((size_t)N_NODES * 4 * 4);
  int* rpf    = (int*)alloc((size_t)(N_NODES + 1) * 4);
  int* rpb    = (int*)alloc((size_t)(N_NODES + 1) * 4);
  int* cf     = (int*)alloc((size_t)N_NODES * 4);
  int* cb     = (int*)alloc((size_t)N_NODES * 4);
  int* adjf   = (int*)alloc((size_t)(N_EDGES + N_NODES) * 4);
  int* adjb   = (int*)alloc((size_t)(N_EDGES + N_NODES) * 4);
  int* bsum   = (int*)alloc(512 * 4);
  int* bsumex = (int*)alloc(512 * 4);
  (void)ws_size; (void)in_sizes; (void)n_in; (void)out_size;

  const int NB = (N_NODES + 255) / 256;   // 196
  const int EB = (N_EDGES + 255) / 256;   // 6250

  k_init_deg<<<NB, 256, 0, stream>>>(cf, cb);
  k_degree<<<EB, 256, 0, stream>>>(ei, cf, cb);
  k_scan1<<<dim3(NB, 2), 256, 0, stream>>>(cf, cb, rpf, rpb, bsum);
  k_scan2<<<dim3(1, 2), 256, 0, stream>>>(bsum, bsumex);
  k_scan3<<<dim3(NB, 2), 256, 0, stream>>>(rpf, rpb, bsumex);
  k_selfloop<<<dim3(NB, 2), 256, 0, stream>>>(rpf, rpb, adjf, adjb, cf, cb);
  k_scatter<<<EB, 256, 0, stream>>>(ei, cf, cb, adjf, adjb);

  k_gemm<<<dim3((N_NODES + 63) / 64, 4), 256, 0, stream>>>(
      x, N_NODES, W_f, W_b, XL, 0, nullptr, nullptr, nullptr, nullptr, nullptr);
  k_scores<<<N_NODES, 64, 0, stream>>>(XL, asf, adf, asb, adb, ALf, ARf, ALb, ARb);
  k_agg<<<dim3(N_NODES, 2), 64, 0, stream>>>(XL, rpf, adjf, rpb, adjb,
                                             ALf, ARf, ALb, ARb, b_f, b_b, H);
  k_gemm<<<dim3((N_NODES + 63) / 64, 4), 256, 0, stream>>>(
      H, N_NODES, W_fu, nullptr, out, 1, b_fu, gam, bet, mean, var);
}

// Round 2
// 606.983 us; speedup vs baseline: 1.6546x; 1.6546x over previous
//
#include <hip/hip_runtime.h>

#define N_NODES 50000
#define N_EDGES 1600000
#define HALF 128
#define NEG_SLOPE 0.2f

// CSR build parameters
#define NBUCK 512
#define NPB 98            // nodes per bucket (512*98 = 50176 >= 50000)
#define CHUNK 6400        // edges per phase-A/C block
#define NBLK 250          // 250*6400 = 1600000 exactly

// ---------------- Phase A: per-block bucket histograms ----------------
__global__ __launch_bounds__(256) void k_hist(const int* __restrict__ ei, int* __restrict__ blockhist) {
  __shared__ int hist[2 * NBUCK];
  const int blk = blockIdx.x, tid = threadIdx.x;
  for (int i = tid; i < 2 * NBUCK; i += 256) hist[i] = 0;
  __syncthreads();
  const int e0 = blk * CHUNK;
  for (int e = e0 + tid; e < e0 + CHUNK; e += 256) {
    int s = ei[e];
    int d = ei[N_EDGES + e];
    atomicAdd(&hist[d / NPB], 1);            // dir 0: group by dst
    atomicAdd(&hist[NBUCK + s / NPB], 1);    // dir 1: group by src
  }
  __syncthreads();
  for (int i = tid; i < 2 * NBUCK; i += 256)
    blockhist[i * NBLK + blk] = hist[i];
}

// ---------------- Phase B1: per-bucket scan over blocks ----------------
__global__ __launch_bounds__(256) void k_rowscan(const int* __restrict__ blockhist,
                                                 int* __restrict__ blockoffs, int* __restrict__ bucktotal) {
  const int i = blockIdx.x;  // 0..1023 = dir*512+bucket
  const int t = threadIdx.x;
  __shared__ int s[256];
  int v = (t < NBLK) ? blockhist[i * NBLK + t] : 0;
  s[t] = v;
  __syncthreads();
  for (int off = 1; off < 256; off <<= 1) {
    int u = (t >= off) ? s[t - off] : 0;
    __syncthreads();
    s[t] += u;
    __syncthreads();
  }
  if (t < NBLK) blockoffs[i * NBLK + t] = s[t] - v;  // exclusive, bucket-local
  if (t == 255) bucktotal[i] = s[255];
}

// ---------------- Phase B2: scan bucket totals (per dir) ----------------
__global__ __launch_bounds__(1024) void k_buckscan(const int* __restrict__ bucktotal,
                                                   int* __restrict__ buckbase, int* rpf, int* rpb) {
  __shared__ int s[1024];
  const int t = threadIdx.x;
  int v = bucktotal[t];
  s[t] = v;
  __syncthreads();
  for (int off = 1; off < 1024; off <<= 1) {
    int u = (t >= off) ? s[t - off] : 0;
    __syncthreads();
    s[t] += u;
    __syncthreads();
  }
  const int dir = t >> 9, b = t & (NBUCK - 1);
  const int sub = dir ? s[NBUCK - 1] : 0;   // total of dir 0 == N_EDGES
  buckbase[dir * (NBUCK + 1) + b] = s[t] - v - sub;
  if (b == NBUCK - 1) buckbase[dir * (NBUCK + 1) + NBUCK] = s[t] - sub;  // == N_EDGES
  if (t == 0) { rpf[N_NODES] = N_EDGES + N_NODES; rpb[N_NODES] = N_EDGES + N_NODES; }
}

// ---------------- Phase C: scatter edges into bucket-contiguous staging ----------------
__global__ __launch_bounds__(256) void k_stage(const int* __restrict__ ei,
                                               const int* __restrict__ blockoffs,
                                               const int* __restrict__ buckbase,
                                               uint2* __restrict__ staging) {
  __shared__ int cur[2 * NBUCK];
  const int blk = blockIdx.x, tid = threadIdx.x;
  for (int i = tid; i < 2 * NBUCK; i += 256) {
    int dir = i >> 9, b = i & (NBUCK - 1);
    cur[i] = blockoffs[i * NBLK + blk] + buckbase[dir * (NBUCK + 1) + b];
  }
  __syncthreads();
  uint2* st0 = staging;
  uint2* st1 = staging + N_EDGES;
  const int e0 = blk * CHUNK;
  for (int e = e0 + tid; e < e0 + CHUNK; e += 256) {
    int s = ei[e];
    int d = ei[N_EDGES + e];
    int p = atomicAdd(&cur[d / NPB], 1);
    st0[p] = make_uint2((unsigned)d, (unsigned)s);
    int q = atomicAdd(&cur[NBUCK + s / NPB], 1);
    st1[q] = make_uint2((unsigned)s, (unsigned)d);
  }
}

// ---------------- Phase D: bin within bucket -> rowptr + adjacency ----------------
__global__ __launch_bounds__(256) void k_bin(const uint2* __restrict__ staging,
                                             const int* __restrict__ buckbase,
                                             int* __restrict__ rpf, int* __restrict__ rpb,
                                             int* __restrict__ adjf, int* __restrict__ adjb) {
  const int b = blockIdx.x, dir = blockIdx.y, tid = threadIdx.x;
  const int node0 = b * NPB;
  if (node0 >= N_NODES) return;
  const int nn = min(NPB, N_NODES - node0);
  const uint2* st = staging + (size_t)dir * N_EDGES;
  int* rp  = dir ? rpb : rpf;
  int* adj = dir ? adjb : adjf;
  const int beg = buckbase[dir * (NBUCK + 1) + b];
  const int end = buckbase[dir * (NBUCK + 1) + b + 1];

  __shared__ int cnt[128];
  __shared__ int sb[128];
  if (tid < 128) cnt[tid] = 0;
  __syncthreads();
  for (int j = beg + tid; j < end; j += 256)
    atomicAdd(&cnt[st[j].x - node0], 1);
  __syncthreads();
  if (tid < 128) sb[tid] = (tid < nn) ? cnt[tid] + 1 : 0;  // +1 = self loop
  __syncthreads();
  for (int off = 1; off < 128; off <<= 1) {
    int u = 0;
    if (tid < 128 && tid >= off) u = sb[tid - off];
    __syncthreads();
    if (tid < 128) sb[tid] += u;
    __syncthreads();
  }
  if (tid < nn) {
    int excl = sb[tid] - (cnt[tid] + 1);
    int r = beg + node0 + excl;      // staged-before + self-loops-before
    rp[node0 + tid] = r;
    adj[r] = node0 + tid;            // self loop first
    cnt[tid] = r + 1;                // cursor for neighbors
  }
  __syncthreads();
  for (int j = beg + tid; j < end; j += 256) {
    uint2 kv = st[j];
    int p = atomicAdd(&cnt[kv.x - node0], 1);
    adj[p] = (int)kv.y;
  }
}

// ---------------- GEMM (M x 256) @ (256 x 256) fp32 tiled ----------------
// mode 0: B = [W_f | W_b] (each ldb=128), output bf16 (packed features)
// mode 1: B = W_fuse (ldb=256), fp32 output with +bias, BN(eval), ReLU

__global__ __launch_bounds__(256) void k_gemm(
    const float* __restrict__ A, int M,
    const float* __restrict__ B0, const float* __restrict__ B1,
    void* __restrict__ Cdst, int mode,
    const float* __restrict__ bias, const float* __restrict__ gamma,
    const float* __restrict__ beta, const float* __restrict__ mean,
    const float* __restrict__ var)
{
  const int tid = threadIdx.x;
  const int m0 = blockIdx.x * 64;
  const int col0 = blockIdx.y * 64;
  const float* B; int bld, bc0;
  if (mode == 0) {
    bld = 128;
    if (col0 < 128) { B = B0; bc0 = col0; } else { B = B1; bc0 = col0 - 128; }
  } else {
    B = B0; bld = 256; bc0 = col0;
  }

  __shared__ float As[16][64];
  __shared__ float Bs[16][64];

  const int mA = tid >> 2, kq = (tid & 3) * 4;
  const int rowA = m0 + mA;
  const float* aptr = A + (size_t)rowA * 256 + kq;
  const int kB = tid >> 4, cB = (tid & 15) * 4;
  const float* bptr = B + (size_t)kB * bld + bc0 + cB;

  const int ty = tid >> 4, tx = tid & 15;
  const int my = ty * 4, cx = tx * 4;
  float acc[4][4];
#pragma unroll
  for (int i = 0; i < 4; ++i)
#pragma unroll
    for (int j = 0; j < 4; ++j) acc[i][j] = 0.f;

  for (int k0 = 0; k0 < 256; k0 += 16) {
    float4 av = make_float4(0.f, 0.f, 0.f, 0.f);
    if (rowA < M) av = *(const float4*)(aptr + k0);
    float4 bv = *(const float4*)(bptr + (size_t)k0 * bld);
    __syncthreads();
    As[kq + 0][mA] = av.x; As[kq + 1][mA] = av.y;
    As[kq + 2][mA] = av.z; As[kq + 3][mA] = av.w;
    *(float4*)&Bs[kB][cB] = bv;
    __syncthreads();
#pragma unroll
    for (int k = 0; k < 16; ++k) {
      float4 a = *(const float4*)&As[k][my];
      float4 b = *(const float4*)&Bs[k][cx];
      acc[0][0] = fmaf(a.x, b.x, acc[0][0]); acc[0][1] = fmaf(a.x, b.y, acc[0][1]);
      acc[0][2] = fmaf(a.x, b.z, acc[0][2]); acc[0][3] = fmaf(a.x, b.w, acc[0][3]);
      acc[1][0] = fmaf(a.y, b.x, acc[1][0]); acc[1][1] = fmaf(a.y, b.y, acc[1][1]);
      acc[1][2] = fmaf(a.y, b.z, acc[1][2]); acc[1][3] = fmaf(a.y, b.w, acc[1][3]);
      acc[2][0] = fmaf(a.z, b.x, acc[2][0]); acc[2][1] = fmaf(a.z, b.y, acc[2][1]);
      acc[2][2] = fmaf(a.z, b.z, acc[2][2]); acc[2][3] = fmaf(a.z, b.w, acc[2][3]);
      acc[3][0] = fmaf(a.w, b.x, acc[3][0]); acc[3][1] = fmaf(a.w, b.y, acc[3][1]);
      acc[3][2] = fmaf(a.w, b.z, acc[3][2]); acc[3][3] = fmaf(a.w, b.w, acc[3][3]);
    }
  }

#pragma unroll
  for (int i = 0; i < 4; ++i) {
    int row = m0 + my + i;
    if (row >= M) continue;
    if (mode == 0) {
      ushort4 h;
      unsigned u;
      u = __float_as_uint(acc[i][0]); u += 0x7FFFu + ((u >> 16) & 1); h.x = (unsigned short)(u >> 16);
      u = __float_as_uint(acc[i][1]); u += 0x7FFFu + ((u >> 16) & 1); h.y = (unsigned short)(u >> 16);
      u = __float_as_uint(acc[i][2]); u += 0x7FFFu + ((u >> 16) & 1); h.z = (unsigned short)(u >> 16);
      u = __float_as_uint(acc[i][3]); u += 0x7FFFu + ((u >> 16) & 1); h.w = (unsigned short)(u >> 16);
      *(ushort4*)((unsigned short*)Cdst + (size_t)row * 256 + col0 + cx) = h;
    } else {
#pragma unroll
      for (int j = 0; j < 4; ++j) {
        int col = col0 + cx + j;
        float v = acc[i][j] + bias[col];
        v = (v - mean[col]) * rsqrtf(var[col] + 1e-5f) * gamma[col] + beta[col];
        ((float*)Cdst)[(size_t)row * 256 + col] = fmaxf(v, 0.f);
      }
    }
  }
}

// ---------------- per-node attention score dots (bf16 features) ----------------
__global__ __launch_bounds__(64) void k_scores(
    const unsigned short* __restrict__ XLh,
    const float* __restrict__ asf, const float* __restrict__ adf,
    const float* __restrict__ asb, const float* __restrict__ adb,
    float* __restrict__ ALf, float* __restrict__ ARf,
    float* __restrict__ ALb, float* __restrict__ ARb)
{
  int n = blockIdx.x;
  int lane = threadIdx.x;
  int hh = lane >> 5;  // 0/1
  int c = lane & 31;
  const unsigned short* row = XLh + (size_t)n * 256;
  float v0 = __uint_as_float((unsigned)row[lane] << 16);
  float v1 = __uint_as_float((unsigned)row[64 + lane] << 16);
  float v2 = __uint_as_float((unsigned)row[128 + lane] << 16);
  float v3 = __uint_as_float((unsigned)row[192 + lane] << 16);
  float s0 = v0 * asf[hh * 32 + c],       d0 = v0 * adf[hh * 32 + c];
  float s1 = v1 * asf[(2 + hh) * 32 + c], d1 = v1 * adf[(2 + hh) * 32 + c];
  float s2 = v2 * asb[hh * 32 + c],       d2 = v2 * adb[hh * 32 + c];
  float s3 = v3 * asb[(2 + hh) * 32 + c], d3 = v3 * adb[(2 + hh) * 32 + c];
#pragma unroll
  for (int off = 16; off > 0; off >>= 1) {
    s0 += __shfl_xor(s0, off, 32); d0 += __shfl_xor(d0, off, 32);
    s1 += __shfl_xor(s1, off, 32); d1 += __shfl_xor(d1, off, 32);
    s2 += __shfl_xor(s2, off, 32); d2 += __shfl_xor(d2, off, 32);
    s3 += __shfl_xor(s3, off, 32); d3 += __shfl_xor(d3, off, 32);
  }
  if (c == 0) {
    ALf[n * 4 + hh] = s0;     ARf[n * 4 + hh] = d0;
    ALf[n * 4 + 2 + hh] = s1; ARf[n * 4 + 2 + hh] = d1;
    ALb[n * 4 + hh] = s2;     ARb[n * 4 + hh] = d2;
    ALb[n * 4 + 2 + hh] = s3; ARb[n * 4 + 2 + hh] = d3;
  }
}

// ---------------- fused softmax + aggregation (one wave per node,dir) ----------------
__global__ __launch_bounds__(64) void k_agg(
    const unsigned short* __restrict__ XLh,
    const int* __restrict__ rpf, const int* __restrict__ adjf,
    const int* __restrict__ rpb, const int* __restrict__ adjb,
    const float* __restrict__ ALf, const float* __restrict__ ARf,
    const float* __restrict__ ALb, const float* __restrict__ ARb,
    const float* __restrict__ bf, const float* __restrict__ bb,
    float* __restrict__ H)
{
  const int n = blockIdx.x;
  const int dir = blockIdx.y;
  const int* rp  = dir ? rpb : rpf;
  const int* adj = dir ? adjb : adjf;
  const float* AL = dir ? ALb : ALf;
  const float* AR = dir ? ARb : ARf;
  const float* bias = dir ? bb : bf;
  const int lane = threadIdx.x;
  const int ch = lane * 2;       // 2 channels per lane (128 per dir)
  const int h = lane >> 4;       // head
  const float arn = AR[n * 4 + h];
  const int beg = rp[n], end = rp[n + 1];
  float accx = 0.f, accy = 0.f, den = 0.f;
  const unsigned* xb = (const unsigned*)XLh + dir * 64 + lane;
  for (int j = beg; j < end; ++j) {
    int nb = adj[j];
    float e = AL[nb * 4 + h] + arn;
    e = (e > 0.f) ? e : NEG_SLOPE * e;
    float w = __expf(e);
    den += w;
    unsigned u = xb[(size_t)nb * 128];
    float vx = __uint_as_float(u << 16);
    float vy = __uint_as_float(u & 0xFFFF0000u);
    accx = fmaf(w, vx, accx);
    accy = fmaf(w, vy, accy);
  }
  float inv = 1.f / (den + 1e-16f);
  float* outp = H + (size_t)n * 256 + dir * HALF + ch;
  float2 r;
  r.x = accx * inv + bias[ch];
  r.y = accy * inv + bias[ch + 1];
  *(float2*)outp = r;
}

// ---------------- launch ----------------

extern "C" void kernel_launch(void* const* d_in, const int* in_sizes, int n_in,
                              void* d_out, int out_size, void* d_ws, size_t ws_size,
                              hipStream_t stream) {
  const float* x    = (const float*)d_in[0];
  const int*   ei   = (const int*)d_in[1];
  const float* W_f  = (const float*)d_in[2];
  const float* asf  = (const float*)d_in[3];
  const float* adf  = (const float*)d_in[4];
  const float* b_f  = (const float*)d_in[5];
  const float* W_b  = (const float*)d_in[6];
  const float* asb  = (const float*)d_in[7];
  const float* adb  = (const float*)d_in[8];
  const float* b_b  = (const float*)d_in[9];
  const float* W_fu = (const float*)d_in[10];
  const float* b_fu = (const float*)d_in[11];
  const float* gam  = (const float*)d_in[12];
  const float* bet  = (const float*)d_in[13];
  const float* mean = (const float*)d_in[14];
  const float* var  = (const float*)d_in[15];
  float* out = (float*)d_out;

  char* base = (char*)d_ws;
  size_t off = 0;
  auto alloc = [&](size_t bytes) {
    void* p = base + off;
    off = (off + bytes + 255) & ~(size_t)255;
    return p;
  };
  float* H               = (float*)alloc((size_t)N_NODES * 256 * 4);
  unsigned short* XLh    = (unsigned short*)alloc((size_t)N_NODES * 256 * 2);
  float* ALf  = (float*)alloc((size_t)N_NODES * 4 * 4);
  float* ARf  = (float*)alloc((size_t)N_NODES * 4 * 4);
  float* ALb  = (float*)alloc((size_t)N_NODES * 4 * 4);
  float* ARb  = (float*)alloc((size_t)N_NODES * 4 * 4);
  int* rpf    = (int*)alloc((size_t)(N_NODES + 1) * 4);
  int* rpb    = (int*)alloc((size_t)(N_NODES + 1) * 4);
  int* adjf   = (int*)alloc((size_t)(N_EDGES + N_NODES) * 4);
  int* adjb   = (int*)alloc((size_t)(N_EDGES + N_NODES) * 4);
  int* blockhist = (int*)alloc((size_t)2 * NBUCK * NBLK * 4);
  int* blockoffs = (int*)alloc((size_t)2 * NBUCK * NBLK * 4);
  int* bucktotal = (int*)alloc((size_t)2 * NBUCK * 4);
  int* buckbase  = (int*)alloc((size_t)2 * (NBUCK + 1) * 4);
  uint2* staging = (uint2*)alloc((size_t)2 * N_EDGES * 8);
  (void)ws_size; (void)in_sizes; (void)n_in; (void)out_size;

  // CSR build (both directions)
  k_hist<<<NBLK, 256, 0, stream>>>(ei, blockhist);
  k_rowscan<<<2 * NBUCK, 256, 0, stream>>>(blockhist, blockoffs, bucktotal);
  k_buckscan<<<1, 1024, 0, stream>>>(bucktotal, buckbase, rpf, rpb);
  k_stage<<<NBLK, 256, 0, stream>>>(ei, blockoffs, buckbase, staging);
  k_bin<<<dim3(NBUCK, 2), 256, 0, stream>>>(staging, buckbase, rpf, rpb, adjf, adjb);

  // projection GEMM -> bf16 features
  k_gemm<<<dim3((N_NODES + 63) / 64, 4), 256, 0, stream>>>(
      x, N_NODES, W_f, W_b, XLh, 0, nullptr, nullptr, nullptr, nullptr, nullptr);
  k_scores<<<N_NODES, 64, 0, stream>>>(XLh, asf, adf, asb, adb, ALf, ARf, ALb, ARb);
  k_agg<<<dim3(N_NODES, 2), 64, 0, stream>>>(XLh, rpf, adjf, rpb, adjb,
                                             ALf, ARf, ALb, ARb, b_f, b_b, H);
  // fusion GEMM + BN + ReLU
  k_gemm<<<dim3((N_NODES + 63) / 64, 4), 256, 0, stream>>>(
      H, N_NODES, W_fu, nullptr, out, 1, b_fu, gam, bet, mean, var);
}

// Round 3
// 467.483 us; speedup vs baseline: 2.1483x; 1.2984x over previous
//
#include <hip/hip_runtime.h>

#define N_NODES 50000
#define N_EDGES 1600000
#define NEG_SLOPE 0.2f

// CSR build parameters
#define NBUCK 512
#define NPB 98            // nodes per bucket (512*98 = 50176 >= 50000)
#define CHUNK 6400        // edges per phase-A/C block
#define NBLK 250          // 250*6400 = 1600000 exactly

typedef __attribute__((ext_vector_type(8))) short short8;
typedef __attribute__((ext_vector_type(4))) float floatx4;

// ---------------- Phase A: per-block bucket histograms ----------------
__global__ __launch_bounds__(256) void k_hist(const int* __restrict__ ei, int* __restrict__ blockhist) {
  __shared__ int hist[2 * NBUCK];
  const int blk = blockIdx.x, tid = threadIdx.x;
  for (int i = tid; i < 2 * NBUCK; i += 256) hist[i] = 0;
  __syncthreads();
  const int e0 = blk * CHUNK;
  for (int e = e0 + tid; e < e0 + CHUNK; e += 256) {
    int s = ei[e];
    int d = ei[N_EDGES + e];
    atomicAdd(&hist[d / NPB], 1);
    atomicAdd(&hist[NBUCK + s / NPB], 1);
  }
  __syncthreads();
  for (int i = tid; i < 2 * NBUCK; i += 256)
    blockhist[i * NBLK + blk] = hist[i];
}

// ---------------- Phase B1: per-bucket scan over blocks ----------------
__global__ __launch_bounds__(256) void k_rowscan(const int* __restrict__ blockhist,
                                                 int* __restrict__ blockoffs, int* __restrict__ bucktotal) {
  const int i = blockIdx.x;
  const int t = threadIdx.x;
  __shared__ int s[256];
  int v = (t < NBLK) ? blockhist[i * NBLK + t] : 0;
  s[t] = v;
  __syncthreads();
  for (int off = 1; off < 256; off <<= 1) {
    int u = (t >= off) ? s[t - off] : 0;
    __syncthreads();
    s[t] += u;
    __syncthreads();
  }
  if (t < NBLK) blockoffs[i * NBLK + t] = s[t] - v;
  if (t == 255) bucktotal[i] = s[255];
}

// ---------------- Phase B2: scan bucket totals (per dir) ----------------
__global__ __launch_bounds__(1024) void k_buckscan(const int* __restrict__ bucktotal,
                                                   int* __restrict__ buckbase, int* rpf, int* rpb) {
  __shared__ int s[1024];
  const int t = threadIdx.x;
  int v = bucktotal[t];
  s[t] = v;
  __syncthreads();
  for (int off = 1; off < 1024; off <<= 1) {
    int u = (t >= off) ? s[t - off] : 0;
    __syncthreads();
    s[t] += u;
    __syncthreads();
  }
  const int dir = t >> 9, b = t & (NBUCK - 1);
  const int sub = dir ? s[NBUCK - 1] : 0;
  buckbase[dir * (NBUCK + 1) + b] = s[t] - v - sub;
  if (b == NBUCK - 1) buckbase[dir * (NBUCK + 1) + NBUCK] = s[t] - sub;
  if (t == 0) { rpf[N_NODES] = N_EDGES + N_NODES; rpb[N_NODES] = N_EDGES + N_NODES; }
}

// ---------------- Phase C: scatter edges into bucket-contiguous staging ----------------
__global__ __launch_bounds__(256) void k_stage(const int* __restrict__ ei,
                                               const int* __restrict__ blockoffs,
                                               const int* __restrict__ buckbase,
                                               uint2* __restrict__ staging) {
  __shared__ int cur[2 * NBUCK];
  const int blk = blockIdx.x, tid = threadIdx.x;
  for (int i = tid; i < 2 * NBUCK; i += 256) {
    int dir = i >> 9, b = i & (NBUCK - 1);
    cur[i] = blockoffs[i * NBLK + blk] + buckbase[dir * (NBUCK + 1) + b];
  }
  __syncthreads();
  uint2* st0 = staging;
  uint2* st1 = staging + N_EDGES;
  const int e0 = blk * CHUNK;
  for (int e = e0 + tid; e < e0 + CHUNK; e += 256) {
    int s = ei[e];
    int d = ei[N_EDGES + e];
    int p = atomicAdd(&cur[d / NPB], 1);
    st0[p] = make_uint2((unsigned)d, (unsigned)s);
    int q = atomicAdd(&cur[NBUCK + s / NPB], 1);
    st1[q] = make_uint2((unsigned)s, (unsigned)d);
  }
}

// ---------------- Phase D: bin within bucket -> rowptr + adjacency ----------------
__global__ __launch_bounds__(256) void k_bin(const uint2* __restrict__ staging,
                                             const int* __restrict__ buckbase,
                                             int* __restrict__ rpf, int* __restrict__ rpb,
                                             int* __restrict__ adjf, int* __restrict__ adjb) {
  const int b = blockIdx.x, dir = blockIdx.y, tid = threadIdx.x;
  const int node0 = b * NPB;
  if (node0 >= N_NODES) return;
  const int nn = min(NPB, N_NODES - node0);
  const uint2* st = staging + (size_t)dir * N_EDGES;
  int* rp  = dir ? rpb : rpf;
  int* adj = dir ? adjb : adjf;
  const int beg = buckbase[dir * (NBUCK + 1) + b];
  const int end = buckbase[dir * (NBUCK + 1) + b + 1];

  __shared__ int cnt[128];
  __shared__ int sb[128];
  if (tid < 128) cnt[tid] = 0;
  __syncthreads();
  for (int j = beg + tid; j < end; j += 256)
    atomicAdd(&cnt[st[j].x - node0], 1);
  __syncthreads();
  if (tid < 128) sb[tid] = (tid < nn) ? cnt[tid] + 1 : 0;
  __syncthreads();
  for (int off = 1; off < 128; off <<= 1) {
    int u = 0;
    if (tid < 128 && tid >= off) u = sb[tid - off];
    __syncthreads();
    if (tid < 128) sb[tid] += u;
    __syncthreads();
  }
  if (tid < nn) {
    int excl = sb[tid] - (cnt[tid] + 1);
    int r = beg + node0 + excl;
    rp[node0 + tid] = r;
    adj[r] = node0 + tid;
    cnt[tid] = r + 1;
  }
  __syncthreads();
  for (int j = beg + tid; j < end; j += 256) {
    uint2 kv = st[j];
    int p = atomicAdd(&cnt[kv.x - node0], 1);
    adj[p] = (int)kv.y;
  }
}

// ---------------- weight prep: fp32 [k][n] -> bf16 [n][k] ----------------
__global__ __launch_bounds__(256) void k_prep(const float* __restrict__ W_f,
                                              const float* __restrict__ W_b,
                                              const float* __restrict__ W_fu,
                                              unsigned short* __restrict__ Bt1,
                                              unsigned short* __restrict__ Bt2) {
  const int k = blockIdx.x;      // 0..255
  const int n = threadIdx.x;     // 0..255
  float w1 = (n < 128) ? W_f[k * 128 + n] : W_b[k * 128 + (n - 128)];
  float w2 = W_fu[k * 256 + n];
  unsigned u1 = __float_as_uint(w1); u1 += 0x7FFFu + ((u1 >> 16) & 1);
  unsigned u2 = __float_as_uint(w2); u2 += 0x7FFFu + ((u2 >> 16) & 1);
  Bt1[(size_t)n * 256 + k] = (unsigned short)(u1 >> 16);
  Bt2[(size_t)n * 256 + k] = (unsigned short)(u2 >> 16);
}

// ---------------- MFMA GEMM: [M x 512'] bf16 @ [512' x 256] bf16 -> 256 cols ----------------
// Effective K=512: k<256 is the "hi" half, k>=256 the "lo" half; B repeats (k&255).
// asplit=1: Asrc is fp32 [M][256], split into hi/lo bf16 on the fly.
// asplit=0: Asrc is bf16 [M][512] (already hi|lo concatenated).
// mode 0: store bf16 to Cdst (XLh). mode 1: +bias, BN, ReLU, fp32 store.
#define LDA 40  // padded LDS k-stride (bf16 elems) per 32-k tile

__global__ __launch_bounds__(256) void k_mm(
    const void* __restrict__ Asrc, int M, int asplit,
    const unsigned short* __restrict__ Bt,   // bf16 [256 n][256 k]
    void* __restrict__ Cdst, int mode,
    const float* __restrict__ bias, const float* __restrict__ gamma,
    const float* __restrict__ beta, const float* __restrict__ mean,
    const float* __restrict__ var)
{
  __shared__ __align__(16) unsigned short As[128 * LDA];
  __shared__ __align__(16) unsigned short Bs[128 * LDA];
  const int tid = threadIdx.x;
  const int m0 = blockIdx.x * 128, col0 = blockIdx.y * 128;
  const int wave = tid >> 6, lane = tid & 63;
  const int wm = wave >> 1, wn = wave & 1;
  const int lm = lane & 15, quad = lane >> 4;

  floatx4 acc[4][4];
#pragma unroll
  for (int i = 0; i < 4; ++i)
#pragma unroll
    for (int j = 0; j < 4; ++j) acc[i][j] = (floatx4){0.f, 0.f, 0.f, 0.f};

  for (int it = 0; it < 16; ++it) {
    const int kk0 = it * 32;
    const int kbase = kk0 & 255;
    __syncthreads();
    if (asplit) {
      const float* A = (const float*)Asrc;
      const bool hi = (kk0 < 256);
#pragma unroll
      for (int q = 0; q < 4; ++q) {
        int idx = q * 256 + tid;            // 0..1023
        int r = idx >> 3, c4 = (idx & 7) * 4;
        float4 v = make_float4(0.f, 0.f, 0.f, 0.f);
        if (m0 + r < M) v = *(const float4*)(A + (size_t)(m0 + r) * 256 + kbase + c4);
        float f[4] = {v.x, v.y, v.z, v.w};
        unsigned short h[4];
#pragma unroll
        for (int i = 0; i < 4; ++i) {
          unsigned u = __float_as_uint(f[i]);
          unsigned uh = u + 0x7FFFu + ((u >> 16) & 1);
          unsigned short hb = (unsigned short)(uh >> 16);
          if (hi) h[i] = hb;
          else {
            float lo = f[i] - __uint_as_float((unsigned)hb << 16);
            unsigned ul = __float_as_uint(lo);
            ul += 0x7FFFu + ((ul >> 16) & 1);
            h[i] = (unsigned short)(ul >> 16);
          }
        }
        *(ushort4*)&As[r * LDA + c4] = make_ushort4(h[0], h[1], h[2], h[3]);
      }
    } else {
      const unsigned short* A = (const unsigned short*)Asrc;
#pragma unroll
      for (int q = 0; q < 2; ++q) {
        int idx = q * 256 + tid;            // 0..511
        int r = idx >> 2, c8 = (idx & 3) * 8;
        ulonglong2 z; z.x = 0; z.y = 0;
        if (m0 + r < M) z = *(const ulonglong2*)(A + (size_t)(m0 + r) * 512 + kk0 + c8);
        *(ulonglong2*)&As[r * LDA + c8] = z;
      }
    }
#pragma unroll
    for (int q = 0; q < 2; ++q) {
      int idx = q * 256 + tid;              // 0..511
      int n = idx >> 2, c8 = (idx & 3) * 8;
      ulonglong2 z = *(const ulonglong2*)(Bt + (size_t)(col0 + n) * 256 + kbase + c8);
      *(ulonglong2*)&Bs[n * LDA + c8] = z;
    }
    __syncthreads();
    short8 a[4], b[4];
#pragma unroll
    for (int i = 0; i < 4; ++i)
      a[i] = *(const short8*)&As[(wm * 64 + i * 16 + lm) * LDA + quad * 8];
#pragma unroll
    for (int j = 0; j < 4; ++j)
      b[j] = *(const short8*)&Bs[(wn * 64 + j * 16 + lm) * LDA + quad * 8];
#pragma unroll
    for (int i = 0; i < 4; ++i)
#pragma unroll
      for (int j = 0; j < 4; ++j)
        acc[i][j] = __builtin_amdgcn_mfma_f32_16x16x32_bf16(a[i], b[j], acc[i][j], 0, 0, 0);
  }

  // epilogue: C/D layout col = lane&15, row = quad*4 + reg
  if (mode == 0) {
    unsigned short* C = (unsigned short*)Cdst;
#pragma unroll
    for (int i = 0; i < 4; ++i) {
#pragma unroll
      for (int j = 0; j < 4; ++j) {
        int gc = col0 + wn * 64 + j * 16 + lm;
#pragma unroll
        for (int reg = 0; reg < 4; ++reg) {
          int gr = m0 + wm * 64 + i * 16 + quad * 4 + reg;
          if (gr < M) {
            unsigned u = __float_as_uint(acc[i][j][reg]);
            u += 0x7FFFu + ((u >> 16) & 1);
            C[(size_t)gr * 256 + gc] = (unsigned short)(u >> 16);
          }
        }
      }
    }
  } else {
    float* C = (float*)Cdst;
#pragma unroll
    for (int j = 0; j < 4; ++j) {
      int gc = col0 + wn * 64 + j * 16 + lm;
      float bi = bias[gc], mu = mean[gc], iv = rsqrtf(var[gc] + 1e-5f);
      float ga = gamma[gc], be = beta[gc];
#pragma unroll
      for (int i = 0; i < 4; ++i) {
#pragma unroll
        for (int reg = 0; reg < 4; ++reg) {
          int gr = m0 + wm * 64 + i * 16 + quad * 4 + reg;
          if (gr < M) {
            float v = acc[i][j][reg] + bi;
            v = (v - mu) * iv * ga + be;
            C[(size_t)gr * 256 + gc] = fmaxf(v, 0.f);
          }
        }
      }
    }
  }
}

// ---------------- per-node attention score dots (bf16 features) ----------------
__global__ __launch_bounds__(64) void k_scores(
    const unsigned short* __restrict__ XLh,
    const float* __restrict__ asf, const float* __restrict__ adf,
    const float* __restrict__ asb, const float* __restrict__ adb,
    float* __restrict__ ALf, float* __restrict__ ARf,
    float* __restrict__ ALb, float* __restrict__ ARb)
{
  int n = blockIdx.x;
  int lane = threadIdx.x;
  int hh = lane >> 5;
  int c = lane & 31;
  const unsigned short* row = XLh + (size_t)n * 256;
  float v0 = __uint_as_float((unsigned)row[lane] << 16);
  float v1 = __uint_as_float((unsigned)row[64 + lane] << 16);
  float v2 = __uint_as_float((unsigned)row[128 + lane] << 16);
  float v3 = __uint_as_float((unsigned)row[192 + lane] << 16);
  float s0 = v0 * asf[hh * 32 + c],       d0 = v0 * adf[hh * 32 + c];
  float s1 = v1 * asf[(2 + hh) * 32 + c], d1 = v1 * adf[(2 + hh) * 32 + c];
  float s2 = v2 * asb[hh * 32 + c],       d2 = v2 * adb[hh * 32 + c];
  float s3 = v3 * asb[(2 + hh) * 32 + c], d3 = v3 * adb[(2 + hh) * 32 + c];
#pragma unroll
  for (int off = 16; off > 0; off >>= 1) {
    s0 += __shfl_xor(s0, off, 32); d0 += __shfl_xor(d0, off, 32);
    s1 += __shfl_xor(s1, off, 32); d1 += __shfl_xor(d1, off, 32);
    s2 += __shfl_xor(s2, off, 32); d2 += __shfl_xor(d2, off, 32);
    s3 += __shfl_xor(s3, off, 32); d3 += __shfl_xor(d3, off, 32);
  }
  if (c == 0) {
    ALf[n * 4 + hh] = s0;     ARf[n * 4 + hh] = d0;
    ALf[n * 4 + 2 + hh] = s1; ARf[n * 4 + 2 + hh] = d1;
    ALb[n * 4 + hh] = s2;     ARb[n * 4 + hh] = d2;
    ALb[n * 4 + 2 + hh] = s3; ARb[n * 4 + 2 + hh] = d3;
  }
}

// ---------------- fused softmax + aggregation, unroll x4 ----------------
// Writes H as hi/lo bf16 pairs packed into Hsp [N][256] dwords:
// dwords [0,128) = hi half (512 bf16 layout cols 0..255), [128,256) = lo half.
__global__ __launch_bounds__(64) void k_agg(
    const unsigned short* __restrict__ XLh,
    const int* __restrict__ rpf, const int* __restrict__ adjf,
    const int* __restrict__ rpb, const int* __restrict__ adjb,
    const float* __restrict__ ALf, const float* __restrict__ ARf,
    const float* __restrict__ ALb, const float* __restrict__ ARb,
    const float* __restrict__ bf, const float* __restrict__ bb,
    unsigned* __restrict__ Hsp)
{
  const int n = blockIdx.x;
  const int dir = blockIdx.y;
  const int* rp  = dir ? rpb : rpf;
  const int* adj = dir ? adjb : adjf;
  const float* AL = dir ? ALb : ALf;
  const float* AR = dir ? ARb : ARf;
  const float* bias = dir ? bb : bf;
  const int lane = threadIdx.x;
  const int ch = lane * 2;
  const int h = lane >> 4;
  const float arn = AR[n * 4 + h];
  const int beg = rp[n], end = rp[n + 1];
  float accx = 0.f, accy = 0.f, den = 0.f;
  const unsigned* xb = (const unsigned*)XLh + dir * 64 + lane;
  int j = beg;
  for (; j + 4 <= end; j += 4) {
    int nb0 = adj[j], nb1 = adj[j + 1], nb2 = adj[j + 2], nb3 = adj[j + 3];
    float al0 = AL[nb0 * 4 + h], al1 = AL[nb1 * 4 + h];
    float al2 = AL[nb2 * 4 + h], al3 = AL[nb3 * 4 + h];
    unsigned u0 = xb[(size_t)nb0 * 128], u1 = xb[(size_t)nb1 * 128];
    unsigned u2 = xb[(size_t)nb2 * 128], u3 = xb[(size_t)nb3 * 128];
    float e0 = al0 + arn; e0 = (e0 > 0.f) ? e0 : NEG_SLOPE * e0; float w0 = __expf(e0);
    float e1 = al1 + arn; e1 = (e1 > 0.f) ? e1 : NEG_SLOPE * e1; float w1 = __expf(e1);
    float e2 = al2 + arn; e2 = (e2 > 0.f) ? e2 : NEG_SLOPE * e2; float w2 = __expf(e2);
    float e3 = al3 + arn; e3 = (e3 > 0.f) ? e3 : NEG_SLOPE * e3; float w3 = __expf(e3);
    den += (w0 + w1) + (w2 + w3);
    accx = fmaf(w0, __uint_as_float(u0 << 16), accx);
    accy = fmaf(w0, __uint_as_float(u0 & 0xFFFF0000u), accy);
    accx = fmaf(w1, __uint_as_float(u1 << 16), accx);
    accy = fmaf(w1, __uint_as_float(u1 & 0xFFFF0000u), accy);
    accx = fmaf(w2, __uint_as_float(u2 << 16), accx);
    accy = fmaf(w2, __uint_as_float(u2 & 0xFFFF0000u), accy);
    accx = fmaf(w3, __uint_as_float(u3 << 16), accx);
    accy = fmaf(w3, __uint_as_float(u3 & 0xFFFF0000u), accy);
  }
  for (; j < end; ++j) {
    int nb = adj[j];
    float e = AL[nb * 4 + h] + arn;
    e = (e > 0.f) ? e : NEG_SLOPE * e;
    float w = __expf(e);
    den += w;
    unsigned u = xb[(size_t)nb * 128];
    accx = fmaf(w, __uint_as_float(u << 16), accx);
    accy = fmaf(w, __uint_as_float(u & 0xFFFF0000u), accy);
  }
  float inv = 1.f / (den + 1e-16f);
  float vx = accx * inv + bias[ch];
  float vy = accy * inv + bias[ch + 1];
  // split into hi/lo bf16
  unsigned ux = __float_as_uint(vx), uy = __float_as_uint(vy);
  unsigned uxh = ux + 0x7FFFu + ((ux >> 16) & 1);
  unsigned uyh = uy + 0x7FFFu + ((uy >> 16) & 1);
  unsigned short hx = (unsigned short)(uxh >> 16), hy = (unsigned short)(uyh >> 16);
  float lx = vx - __uint_as_float((unsigned)hx << 16);
  float ly = vy - __uint_as_float((unsigned)hy << 16);
  unsigned ulx = __float_as_uint(lx); ulx += 0x7FFFu + ((ulx >> 16) & 1);
  unsigned uly = __float_as_uint(ly); uly += 0x7FFFu + ((uly >> 16) & 1);
  unsigned hiw = ((unsigned)hy << 16) | hx;
  unsigned low = (uly & 0xFFFF0000u) | (ulx >> 16);
  Hsp[(size_t)n * 256 + dir * 64 + lane] = hiw;
  Hsp[(size_t)n * 256 + 128 + dir * 64 + lane] = low;
}

// ---------------- launch ----------------

extern "C" void kernel_launch(void* const* d_in, const int* in_sizes, int n_in,
                              void* d_out, int out_size, void* d_ws, size_t ws_size,
                              hipStream_t stream) {
  const float* x    = (const float*)d_in[0];
  const int*   ei   = (const int*)d_in[1];
  const float* W_f  = (const float*)d_in[2];
  const float* asf  = (const float*)d_in[3];
  const float* adf  = (const float*)d_in[4];
  const float* b_f  = (const float*)d_in[5];
  const float* W_b  = (const float*)d_in[6];
  const float* asb  = (const float*)d_in[7];
  const float* adb  = (const float*)d_in[8];
  const float* b_b  = (const float*)d_in[9];
  const float* W_fu = (const float*)d_in[10];
  const float* b_fu = (const float*)d_in[11];
  const float* gam  = (const float*)d_in[12];
  const float* bet  = (const float*)d_in[13];
  const float* mean = (const float*)d_in[14];
  const float* var  = (const float*)d_in[15];
  float* out = (float*)d_out;

  char* base = (char*)d_ws;
  size_t off = 0;
  auto alloc = [&](size_t bytes) {
    void* p = base + off;
    off = (off + bytes + 255) & ~(size_t)255;
    return p;
  };
  unsigned* Hsp          = (unsigned*)alloc((size_t)N_NODES * 256 * 4);       // hi/lo bf16 [N][512]
  unsigned short* XLh    = (unsigned short*)alloc((size_t)N_NODES * 256 * 2);
  unsigned short* Bt1    = (unsigned short*)alloc((size_t)256 * 256 * 2);
  unsigned short* Bt2    = (unsigned short*)alloc((size_t)256 * 256 * 2);
  float* ALf  = (float*)alloc((size_t)N_NODES * 4 * 4);
  float* ARf  = (float*)alloc((size_t)N_NODES * 4 * 4);
  float* ALb  = (float*)alloc((size_t)N_NODES * 4 * 4);
  float* ARb  = (float*)alloc((size_t)N_NODES * 4 * 4);
  int* rpf    = (int*)alloc((size_t)(N_NODES + 1) * 4);
  int* rpb    = (int*)alloc((size_t)(N_NODES + 1) * 4);
  int* adjf   = (int*)alloc((size_t)(N_EDGES + N_NODES) * 4);
  int* adjb   = (int*)alloc((size_t)(N_EDGES + N_NODES) * 4);
  int* blockhist = (int*)alloc((size_t)2 * NBUCK * NBLK * 4);
  int* blockoffs = (int*)alloc((size_t)2 * NBUCK * NBLK * 4);
  int* bucktotal = (int*)alloc((size_t)2 * NBUCK * 4);
  int* buckbase  = (int*)alloc((size_t)2 * (NBUCK + 1) * 4);
  uint2* staging = (uint2*)alloc((size_t)2 * N_EDGES * 8);
  (void)ws_size; (void)in_sizes; (void)n_in; (void)out_size;

  // weight prep + CSR build
  k_prep<<<256, 256, 0, stream>>>(W_f, W_b, W_fu, Bt1, Bt2);
  k_hist<<<NBLK, 256, 0, stream>>>(ei, blockhist);
  k_rowscan<<<2 * NBUCK, 256, 0, stream>>>(blockhist, blockoffs, bucktotal);
  k_buckscan<<<1, 1024, 0, stream>>>(bucktotal, buckbase, rpf, rpb);
  k_stage<<<NBLK, 256, 0, stream>>>(ei, blockoffs, buckbase, staging);
  k_bin<<<dim3(NBUCK, 2), 256, 0, stream>>>(staging, buckbase, rpf, rpb, adjf, adjb);

  const int MB = (N_NODES + 127) / 128;  // 391
  // projection GEMM (fp32 x, split-bf16) -> bf16 features
  k_mm<<<dim3(MB, 2), 256, 0, stream>>>(x, N_NODES, 1, Bt1, XLh, 0,
                                        nullptr, nullptr, nullptr, nullptr, nullptr);
  k_scores<<<N_NODES, 64, 0, stream>>>(XLh, asf, adf, asb, adb, ALf, ARf, ALb, ARb);
  k_agg<<<dim3(N_NODES, 2), 64, 0, stream>>>(XLh, rpf, adjf, rpb, adjb,
                                             ALf, ARf, ALb, ARb, b_f, b_b, Hsp);
  // fusion GEMM (split-bf16 H) + bias + BN + ReLU
  k_mm<<<dim3(MB, 2), 256, 0, stream>>>(Hsp, N_NODES, 0, Bt2, out, 1,
                                        b_fu, gam, bet, mean, var);
}

// Round 4
// 463.842 us; speedup vs baseline: 2.1652x; 1.0079x over previous
//
#include <hip/hip_runtime.h>

#define N_NODES 50000
#define N_EDGES 1600000
#define NEG_SLOPE 0.2f

// CSR build parameters: pow2 node buckets
#define NBUCK 98          // ceil(50000/512)
#define BSH 9             // bucket = node >> 9 (NPB = 512)
#define NPB 512
#define CHUNK 6400        // edges per phase-A/C block
#define NBLK 250          // 250*6400 = 1600000 exactly

typedef __attribute__((ext_vector_type(8))) short short8;
typedef __attribute__((ext_vector_type(4))) float floatx4;

// ---------------- Phase A: per-block bucket histograms ----------------
__global__ __launch_bounds__(256) void k_hist(const int* __restrict__ ei, int* __restrict__ blockhist) {
  __shared__ int hist[2 * NBUCK];
  const int blk = blockIdx.x, tid = threadIdx.x;
  for (int i = tid; i < 2 * NBUCK; i += 256) hist[i] = 0;
  __syncthreads();
  const int e0 = blk * CHUNK;
  for (int e = e0 + tid; e < e0 + CHUNK; e += 256) {
    int s = ei[e];
    int d = ei[N_EDGES + e];
    atomicAdd(&hist[d >> BSH], 1);            // dir 0: group by dst
    atomicAdd(&hist[NBUCK + (s >> BSH)], 1);  // dir 1: group by src
  }
  __syncthreads();
  for (int i = tid; i < 2 * NBUCK; i += 256)
    blockhist[i * NBLK + blk] = hist[i];
}

// ---------------- Phase B1: per-bucket scan over blocks ----------------
__global__ __launch_bounds__(256) void k_rowscan(const int* __restrict__ blockhist,
                                                 int* __restrict__ blockoffs, int* __restrict__ bucktotal) {
  const int i = blockIdx.x;  // 0..2*NBUCK-1
  const int t = threadIdx.x;
  __shared__ int s[256];
  int v = (t < NBLK) ? blockhist[i * NBLK + t] : 0;
  s[t] = v;
  __syncthreads();
  for (int off = 1; off < 256; off <<= 1) {
    int u = (t >= off) ? s[t - off] : 0;
    __syncthreads();
    s[t] += u;
    __syncthreads();
  }
  if (t < NBLK) blockoffs[i * NBLK + t] = s[t] - v;
  if (t == 255) bucktotal[i] = s[255];
}

// ---------------- Phase B2: scan bucket totals (per dir) ----------------
__global__ __launch_bounds__(256) void k_buckscan(const int* __restrict__ bucktotal,
                                                  int* __restrict__ buckbase, int* rpf, int* rpb) {
  __shared__ int s[256];
  const int t = threadIdx.x;
  int v = (t < 2 * NBUCK) ? bucktotal[t] : 0;
  s[t] = v;
  __syncthreads();
  for (int off = 1; off < 256; off <<= 1) {
    int u = (t >= off) ? s[t - off] : 0;
    __syncthreads();
    s[t] += u;
    __syncthreads();
  }
  if (t < 2 * NBUCK) {
    const int dir = (t >= NBUCK) ? 1 : 0;
    const int b = t - dir * NBUCK;
    const int sub = dir ? s[NBUCK - 1] : 0;   // dir0 total == N_EDGES
    buckbase[dir * (NBUCK + 1) + b] = s[t] - v - sub;
    if (b == NBUCK - 1) buckbase[dir * (NBUCK + 1) + NBUCK] = s[t] - sub;
  }
  if (t == 0) { rpf[N_NODES] = N_EDGES + N_NODES; rpb[N_NODES] = N_EDGES + N_NODES; }
}

// ---------------- Phase C: scatter edges into bucket-contiguous staging ----------------
__global__ __launch_bounds__(256) void k_stage(const int* __restrict__ ei,
                                               const int* __restrict__ blockoffs,
                                               const int* __restrict__ buckbase,
                                               uint2* __restrict__ staging) {
  __shared__ int cur[2 * NBUCK];
  const int blk = blockIdx.x, tid = threadIdx.x;
  for (int i = tid; i < 2 * NBUCK; i += 256) {
    int dir = (i >= NBUCK) ? 1 : 0;
    int b = i - dir * NBUCK;
    cur[i] = blockoffs[i * NBLK + blk] + buckbase[dir * (NBUCK + 1) + b];
  }
  __syncthreads();
  uint2* st0 = staging;
  uint2* st1 = staging + N_EDGES;
  const int e0 = blk * CHUNK;
  for (int e = e0 + tid; e < e0 + CHUNK; e += 256) {
    int s = ei[e];
    int d = ei[N_EDGES + e];
    int p = atomicAdd(&cur[d >> BSH], 1);
    st0[p] = make_uint2((unsigned)d, (unsigned)s);
    int q = atomicAdd(&cur[NBUCK + (s >> BSH)], 1);
    st1[q] = make_uint2((unsigned)s, (unsigned)d);
  }
}

// ---------------- Phase D: bin within bucket -> rowptr + adjacency ----------------
__global__ __launch_bounds__(1024) void k_bin(const uint2* __restrict__ staging,
                                              const int* __restrict__ buckbase,
                                              int* __restrict__ rpf, int* __restrict__ rpb,
                                              int* __restrict__ adjf, int* __restrict__ adjb) {
  const int b = blockIdx.x, dir = blockIdx.y, tid = threadIdx.x;
  const int node0 = b << BSH;
  const int nn = min(NPB, N_NODES - node0);
  const uint2* st = staging + (size_t)dir * N_EDGES;
  int* rp  = dir ? rpb : rpf;
  int* adj = dir ? adjb : adjf;
  const int beg = buckbase[dir * (NBUCK + 1) + b];
  const int end = buckbase[dir * (NBUCK + 1) + b + 1];

  __shared__ int cnt[NPB];
  __shared__ int sb[NPB];
  if (tid < NPB) cnt[tid] = 0;
  __syncthreads();
  for (int j = beg + tid; j < end; j += 1024)
    atomicAdd(&cnt[st[j].x - node0], 1);
  __syncthreads();
  if (tid < NPB) sb[tid] = (tid < nn) ? cnt[tid] + 1 : 0;  // +1 = self loop
  __syncthreads();
  for (int off = 1; off < NPB; off <<= 1) {
    int u = 0;
    if (tid < NPB && tid >= off) u = sb[tid - off];
    __syncthreads();
    if (tid < NPB) sb[tid] += u;
    __syncthreads();
  }
  if (tid < nn) {
    int excl = sb[tid] - (cnt[tid] + 1);
    int r = beg + node0 + excl;      // staged-before + self-loops-before
    rp[node0 + tid] = r;
    adj[r] = node0 + tid;            // self loop first
    cnt[tid] = r + 1;                // cursor for neighbors
  }
  __syncthreads();
  for (int j = beg + tid; j < end; j += 1024) {
    uint2 kv = st[j];
    int p = atomicAdd(&cnt[kv.x - node0], 1);
    adj[p] = (int)kv.y;
  }
}

// ---------------- weight prep: fp32 [k][n] -> bf16 [n][k] ----------------
__global__ __launch_bounds__(256) void k_prep(const float* __restrict__ W_f,
                                              const float* __restrict__ W_b,
                                              const float* __restrict__ W_fu,
                                              unsigned short* __restrict__ Bt1,
                                              unsigned short* __restrict__ Bt2) {
  const int k = blockIdx.x;      // 0..255
  const int n = threadIdx.x;     // 0..255
  float w1 = (n < 128) ? W_f[k * 128 + n] : W_b[k * 128 + (n - 128)];
  float w2 = W_fu[k * 256 + n];
  unsigned u1 = __float_as_uint(w1); u1 += 0x7FFFu + ((u1 >> 16) & 1);
  unsigned u2 = __float_as_uint(w2); u2 += 0x7FFFu + ((u2 >> 16) & 1);
  Bt1[(size_t)n * 256 + k] = (unsigned short)(u1 >> 16);
  Bt2[(size_t)n * 256 + k] = (unsigned short)(u2 >> 16);
}

// ---------------- MFMA GEMM: [M x 512'] bf16 @ [512' x 256] bf16 ----------------
// Effective K=512: k<256 "hi" half, k>=256 "lo" half; B repeats (k&255).
// asplit=1: Asrc fp32 [M][256], split hi/lo on the fly. asplit=0: bf16 [M][512].
// mode 0: bf16 store. mode 1: +bias, BN, ReLU, fp32 store.
#define LDA 40

__global__ __launch_bounds__(256) void k_mm(
    const void* __restrict__ Asrc, int M, int asplit,
    const unsigned short* __restrict__ Bt,
    void* __restrict__ Cdst, int mode,
    const float* __restrict__ bias, const float* __restrict__ gamma,
    const float* __restrict__ beta, const float* __restrict__ mean,
    const float* __restrict__ var)
{
  __shared__ __align__(16) unsigned short As[128 * LDA];
  __shared__ __align__(16) unsigned short Bs[128 * LDA];
  const int tid = threadIdx.x;
  const int m0 = blockIdx.x * 128, col0 = blockIdx.y * 128;
  const int wave = tid >> 6, lane = tid & 63;
  const int wm = wave >> 1, wn = wave & 1;
  const int lm = lane & 15, quad = lane >> 4;

  floatx4 acc[4][4];
#pragma unroll
  for (int i = 0; i < 4; ++i)
#pragma unroll
    for (int j = 0; j < 4; ++j) acc[i][j] = (floatx4){0.f, 0.f, 0.f, 0.f};

  for (int it = 0; it < 16; ++it) {
    const int kk0 = it * 32;
    const int kbase = kk0 & 255;
    __syncthreads();
    if (asplit) {
      const float* A = (const float*)Asrc;
      const bool hi = (kk0 < 256);
#pragma unroll
      for (int q = 0; q < 4; ++q) {
        int idx = q * 256 + tid;
        int r = idx >> 3, c4 = (idx & 7) * 4;
        float4 v = make_float4(0.f, 0.f, 0.f, 0.f);
        if (m0 + r < M) v = *(const float4*)(A + (size_t)(m0 + r) * 256 + kbase + c4);
        float f[4] = {v.x, v.y, v.z, v.w};
        unsigned short h[4];
#pragma unroll
        for (int i = 0; i < 4; ++i) {
          unsigned u = __float_as_uint(f[i]);
          unsigned uh = u + 0x7FFFu + ((u >> 16) & 1);
          unsigned short hb = (unsigned short)(uh >> 16);
          if (hi) h[i] = hb;
          else {
            float lo = f[i] - __uint_as_float((unsigned)hb << 16);
            unsigned ul = __float_as_uint(lo);
            ul += 0x7FFFu + ((ul >> 16) & 1);
            h[i] = (unsigned short)(ul >> 16);
          }
        }
        *(ushort4*)&As[r * LDA + c4] = make_ushort4(h[0], h[1], h[2], h[3]);
      }
    } else {
      const unsigned short* A = (const unsigned short*)Asrc;
#pragma unroll
      for (int q = 0; q < 2; ++q) {
        int idx = q * 256 + tid;
        int r = idx >> 2, c8 = (idx & 3) * 8;
        ulonglong2 z; z.x = 0; z.y = 0;
        if (m0 + r < M) z = *(const ulonglong2*)(A + (size_t)(m0 + r) * 512 + kk0 + c8);
        *(ulonglong2*)&As[r * LDA + c8] = z;
      }
    }
#pragma unroll
    for (int q = 0; q < 2; ++q) {
      int idx = q * 256 + tid;
      int n = idx >> 2, c8 = (idx & 3) * 8;
      ulonglong2 z = *(const ulonglong2*)(Bt + (size_t)(col0 + n) * 256 + kbase + c8);
      *(ulonglong2*)&Bs[n * LDA + c8] = z;
    }
    __syncthreads();
    short8 a[4], b[4];
#pragma unroll
    for (int i = 0; i < 4; ++i)
      a[i] = *(const short8*)&As[(wm * 64 + i * 16 + lm) * LDA + quad * 8];
#pragma unroll
    for (int j = 0; j < 4; ++j)
      b[j] = *(const short8*)&Bs[(wn * 64 + j * 16 + lm) * LDA + quad * 8];
#pragma unroll
    for (int i = 0; i < 4; ++i)
#pragma unroll
      for (int j = 0; j < 4; ++j)
        acc[i][j] = __builtin_amdgcn_mfma_f32_16x16x32_bf16(a[i], b[j], acc[i][j], 0, 0, 0);
  }

  if (mode == 0) {
    unsigned short* C = (unsigned short*)Cdst;
#pragma unroll
    for (int i = 0; i < 4; ++i) {
#pragma unroll
      for (int j = 0; j < 4; ++j) {
        int gc = col0 + wn * 64 + j * 16 + lm;
#pragma unroll
        for (int reg = 0; reg < 4; ++reg) {
          int gr = m0 + wm * 64 + i * 16 + quad * 4 + reg;
          if (gr < M) {
            unsigned u = __float_as_uint(acc[i][j][reg]);
            u += 0x7FFFu + ((u >> 16) & 1);
            C[(size_t)gr * 256 + gc] = (unsigned short)(u >> 16);
          }
        }
      }
    }
  } else {
    float* C = (float*)Cdst;
#pragma unroll
    for (int j = 0; j < 4; ++j) {
      int gc = col0 + wn * 64 + j * 16 + lm;
      float bi = bias[gc], mu = mean[gc], iv = rsqrtf(var[gc] + 1e-5f);
      float ga = gamma[gc], be = beta[gc];
#pragma unroll
      for (int i = 0; i < 4; ++i) {
#pragma unroll
        for (int reg = 0; reg < 4; ++reg) {
          int gr = m0 + wm * 64 + i * 16 + quad * 4 + reg;
          if (gr < M) {
            float v = acc[i][j][reg] + bi;
            v = (v - mu) * iv * ga + be;
            C[(size_t)gr * 256 + gc] = fmaxf(v, 0.f);
          }
        }
      }
    }
  }
}

// ---------------- per-node attention score dots (bf16 features) ----------------
__global__ __launch_bounds__(64) void k_scores(
    const unsigned short* __restrict__ XLh,
    const float* __restrict__ asf, const float* __restrict__ adf,
    const float* __restrict__ asb, const float* __restrict__ adb,
    float* __restrict__ ALf, float* __restrict__ ARf,
    float* __restrict__ ALb, float* __restrict__ ARb)
{
  int n = blockIdx.x;
  int lane = threadIdx.x;
  int hh = lane >> 5;
  int c = lane & 31;
  const unsigned short* row = XLh + (size_t)n * 256;
  float v0 = __uint_as_float((unsigned)row[lane] << 16);
  float v1 = __uint_as_float((unsigned)row[64 + lane] << 16);
  float v2 = __uint_as_float((unsigned)row[128 + lane] << 16);
  float v3 = __uint_as_float((unsigned)row[192 + lane] << 16);
  float s0 = v0 * asf[hh * 32 + c],       d0 = v0 * adf[hh * 32 + c];
  float s1 = v1 * asf[(2 + hh) * 32 + c], d1 = v1 * adf[(2 + hh) * 32 + c];
  float s2 = v2 * asb[hh * 32 + c],       d2 = v2 * adb[hh * 32 + c];
  float s3 = v3 * asb[(2 + hh) * 32 + c], d3 = v3 * adb[(2 + hh) * 32 + c];
#pragma unroll
  for (int off = 16; off > 0; off >>= 1) {
    s0 += __shfl_xor(s0, off, 32); d0 += __shfl_xor(d0, off, 32);
    s1 += __shfl_xor(s1, off, 32); d1 += __shfl_xor(d1, off, 32);
    s2 += __shfl_xor(s2, off, 32); d2 += __shfl_xor(d2, off, 32);
    s3 += __shfl_xor(s3, off, 32); d3 += __shfl_xor(d3, off, 32);
  }
  if (c == 0) {
    ALf[n * 4 + hh] = s0;     ARf[n * 4 + hh] = d0;
    ALf[n * 4 + 2 + hh] = s1; ARf[n * 4 + 2 + hh] = d1;
    ALb[n * 4 + hh] = s2;     ARb[n * 4 + hh] = d2;
    ALb[n * 4 + 2 + hh] = s3; ARb[n * 4 + 2 + hh] = d3;
  }
}

// ---------------- fused softmax + aggregation, unroll x4, 32-bit offsets ----------------
__global__ __launch_bounds__(64) void k_agg(
    const unsigned short* __restrict__ XLh,
    const int* __restrict__ rpf, const int* __restrict__ adjf,
    const int* __restrict__ rpb, const int* __restrict__ adjb,
    const float* __restrict__ ALf, const float* __restrict__ ARf,
    const float* __restrict__ ALb, const float* __restrict__ ARb,
    const float* __restrict__ bf, const float* __restrict__ bb,
    unsigned* __restrict__ Hsp)
{
  const int n = blockIdx.x;
  const int dir = blockIdx.y;
  const int* rp  = dir ? rpb : rpf;
  const int* adj = dir ? adjb : adjf;
  const float* AL = dir ? ALb : ALf;
  const float* AR = dir ? ARb : ARf;
  const float* bias = dir ? bb : bf;
  const int lane = threadIdx.x;
  const int ch = lane * 2;
  const unsigned h = (unsigned)(lane >> 4);
  const float arn = AR[n * 4 + (int)h];
  const int beg = rp[n], end = rp[n + 1];
  float accx = 0.f, accy = 0.f, den = 0.f;
  const unsigned* XLu = (const unsigned*)XLh;
  const unsigned fb = (unsigned)(dir * 64 + lane);   // dword offset within row
  int j = beg;
  for (; j + 4 <= end; j += 4) {
    int nb0 = adj[j], nb1 = adj[j + 1], nb2 = adj[j + 2], nb3 = adj[j + 3];
    float al0 = AL[((unsigned)nb0 << 2) | h], al1 = AL[((unsigned)nb1 << 2) | h];
    float al2 = AL[((unsigned)nb2 << 2) | h], al3 = AL[((unsigned)nb3 << 2) | h];
    unsigned u0 = XLu[((unsigned)nb0 << 7) | fb], u1 = XLu[((unsigned)nb1 << 7) | fb];
    unsigned u2 = XLu[((unsigned)nb2 << 7) | fb], u3 = XLu[((unsigned)nb3 << 7) | fb];
    float e0 = al0 + arn; e0 = (e0 > 0.f) ? e0 : NEG_SLOPE * e0; float w0 = __expf(e0);
    float e1 = al1 + arn; e1 = (e1 > 0.f) ? e1 : NEG_SLOPE * e1; float w1 = __expf(e1);
    float e2 = al2 + arn; e2 = (e2 > 0.f) ? e2 : NEG_SLOPE * e2; float w2 = __expf(e2);
    float e3 = al3 + arn; e3 = (e3 > 0.f) ? e3 : NEG_SLOPE * e3; float w3 = __expf(e3);
    den += (w0 + w1) + (w2 + w3);
    accx = fmaf(w0, __uint_as_float(u0 << 16), accx);
    accy = fmaf(w0, __uint_as_float(u0 & 0xFFFF0000u), accy);
    accx = fmaf(w1, __uint_as_float(u1 << 16), accx);
    accy = fmaf(w1, __uint_as_float(u1 & 0xFFFF0000u), accy);
    accx = fmaf(w2, __uint_as_float(u2 << 16), accx);
    accy = fmaf(w2, __uint_as_float(u2 & 0xFFFF0000u), accy);
    accx = fmaf(w3, __uint_as_float(u3 << 16), accx);
    accy = fmaf(w3, __uint_as_float(u3 & 0xFFFF0000u), accy);
  }
  for (; j < end; ++j) {
    int nb = adj[j];
    float e = AL[((unsigned)nb << 2) | h] + arn;
    e = (e > 0.f) ? e : NEG_SLOPE * e;
    float w = __expf(e);
    den += w;
    unsigned u = XLu[((unsigned)nb << 7) | fb];
    accx = fmaf(w, __uint_as_float(u << 16), accx);
    accy = fmaf(w, __uint_as_float(u & 0xFFFF0000u), accy);
  }
  float inv = 1.f / (den + 1e-16f);
  float vx = accx * inv + bias[ch];
  float vy = accy * inv + bias[ch + 1];
  unsigned ux = __float_as_uint(vx), uy = __float_as_uint(vy);
  unsigned uxh = ux + 0x7FFFu + ((ux >> 16) & 1);
  unsigned uyh = uy + 0x7FFFu + ((uy >> 16) & 1);
  unsigned short hx = (unsigned short)(uxh >> 16), hy = (unsigned short)(uyh >> 16);
  float lx = vx - __uint_as_float((unsigned)hx << 16);
  float ly = vy - __uint_as_float((unsigned)hy << 16);
  unsigned ulx = __float_as_uint(lx); ulx += 0x7FFFu + ((ulx >> 16) & 1);
  unsigned uly = __float_as_uint(ly); uly += 0x7FFFu + ((uly >> 16) & 1);
  unsigned hiw = ((unsigned)hy << 16) | hx;
  unsigned low = (uly & 0xFFFF0000u) | (ulx >> 16);
  Hsp[(size_t)n * 256 + dir * 64 + lane] = hiw;
  Hsp[(size_t)n * 256 + 128 + dir * 64 + lane] = low;
}

// ---------------- launch ----------------

extern "C" void kernel_launch(void* const* d_in, const int* in_sizes, int n_in,
                              void* d_out, int out_size, void* d_ws, size_t ws_size,
                              hipStream_t stream) {
  const float* x    = (const float*)d_in[0];
  const int*   ei   = (const int*)d_in[1];
  const float* W_f  = (const float*)d_in[2];
  const float* asf  = (const float*)d_in[3];
  const float* adf  = (const float*)d_in[4];
  const float* b_f  = (const float*)d_in[5];
  const float* W_b  = (const float*)d_in[6];
  const float* asb  = (const float*)d_in[7];
  const float* adb  = (const float*)d_in[8];
  const float* b_b  = (const float*)d_in[9];
  const float* W_fu = (const float*)d_in[10];
  const float* b_fu = (const float*)d_in[11];
  const float* gam  = (const float*)d_in[12];
  const float* bet  = (const float*)d_in[13];
  const float* mean = (const float*)d_in[14];
  const float* var  = (const float*)d_in[15];
  float* out = (float*)d_out;

  char* base = (char*)d_ws;
  size_t off = 0;
  auto alloc = [&](size_t bytes) {
    void* p = base + off;
    off = (off + bytes + 255) & ~(size_t)255;
    return p;
  };
  unsigned* Hsp          = (unsigned*)alloc((size_t)N_NODES * 256 * 4);       // hi/lo bf16 [N][512]
  unsigned short* XLh    = (unsigned short*)alloc((size_t)N_NODES * 256 * 2);
  unsigned short* Bt1    = (unsigned short*)alloc((size_t)256 * 256 * 2);
  unsigned short* Bt2    = (unsigned short*)alloc((size_t)256 * 256 * 2);
  float* ALf  = (float*)alloc((size_t)N_NODES * 4 * 4);
  float* ARf  = (float*)alloc((size_t)N_NODES * 4 * 4);
  float* ALb  = (float*)alloc((size_t)N_NODES * 4 * 4);
  float* ARb  = (float*)alloc((size_t)N_NODES * 4 * 4);
  int* rpf    = (int*)alloc((size_t)(N_NODES + 1) * 4);
  int* rpb    = (int*)alloc((size_t)(N_NODES + 1) * 4);
  int* adjf   = (int*)alloc((size_t)(N_EDGES + N_NODES) * 4);
  int* adjb   = (int*)alloc((size_t)(N_EDGES + N_NODES) * 4);
  int* blockhist = (int*)alloc((size_t)2 * NBUCK * NBLK * 4);
  int* blockoffs = (int*)alloc((size_t)2 * NBUCK * NBLK * 4);
  int* bucktotal = (int*)alloc((size_t)2 * NBUCK * 4);
  int* buckbase  = (int*)alloc((size_t)2 * (NBUCK + 1) * 4);
  uint2* staging = (uint2*)alloc((size_t)2 * N_EDGES * 8);
  (void)ws_size; (void)in_sizes; (void)n_in; (void)out_size;

  // weight prep + CSR build
  k_prep<<<256, 256, 0, stream>>>(W_f, W_b, W_fu, Bt1, Bt2);
  k_hist<<<NBLK, 256, 0, stream>>>(ei, blockhist);
  k_rowscan<<<2 * NBUCK, 256, 0, stream>>>(blockhist, blockoffs, bucktotal);
  k_buckscan<<<1, 256, 0, stream>>>(bucktotal, buckbase, rpf, rpb);
  k_stage<<<NBLK, 256, 0, stream>>>(ei, blockoffs, buckbase, staging);
  k_bin<<<dim3(NBUCK, 2), 1024, 0, stream>>>(staging, buckbase, rpf, rpb, adjf, adjb);

  const int MB = (N_NODES + 127) / 128;  // 391
  // projection GEMM (fp32 x, split-bf16) -> bf16 features
  k_mm<<<dim3(MB, 2), 256, 0, stream>>>(x, N_NODES, 1, Bt1, XLh, 0,
                                        nullptr, nullptr, nullptr, nullptr, nullptr);
  k_scores<<<N_NODES, 64, 0, stream>>>(XLh, asf, adf, asb, adb, ALf, ARf, ALb, ARb);
  k_agg<<<dim3(N_NODES, 2), 64, 0, stream>>>(XLh, rpf, adjf, rpb, adjb,
                                             ALf, ARf, ALb, ARb, b_f, b_b, Hsp);
  // fusion GEMM (split-bf16 H) + bias + BN + ReLU
  k_mm<<<dim3(MB, 2), 256, 0, stream>>>(Hsp, N_NODES, 0, Bt2, out, 1,
                                        b_fu, gam, bet, mean, var);
}

// Round 5
// 430.056 us; speedup vs baseline: 2.3353x; 1.0786x over previous
//
#include <hip/hip_runtime.h>

#define N_NODES 50000
#define N_EDGES 1600000
#define NEG_SLOPE 0.2f

// CSR build parameters: pow2 node buckets
#define NBUCK 98          // ceil(50000/512)
#define BSH 9             // bucket = node >> 9
#define NPB 512
#define CHUNK 6400
#define NBLK 250          // 250*6400 = 1600000

typedef __attribute__((ext_vector_type(8))) short short8;
typedef __attribute__((ext_vector_type(4))) float floatx4;

__device__ __forceinline__ unsigned short f2bf(float f) {
  unsigned u = __float_as_uint(f);
  u += 0x7FFFu + ((u >> 16) & 1);
  return (unsigned short)(u >> 16);
}
__device__ __forceinline__ float bflo(unsigned u) { return __uint_as_float(u << 16); }
__device__ __forceinline__ float bfhi(unsigned u) { return __uint_as_float(u & 0xFFFF0000u); }

// ---------------- setup: edge histograms + weight prep + x hi/lo split ----------------
__global__ __launch_bounds__(256) void k_setup(
    const int* __restrict__ ei, int* __restrict__ blockhist,
    const float* __restrict__ W_f, const float* __restrict__ W_b,
    const float* __restrict__ W_fu,
    unsigned short* __restrict__ Bt1, unsigned short* __restrict__ Bt2,
    const float* __restrict__ x, unsigned short* __restrict__ Xsp)
{
  const int tid = threadIdx.x;
  if (blockIdx.x >= NBLK + 256) {
    // ---- split x into hi/lo bf16 [N][512] ----
    const unsigned gid = (unsigned)(blockIdx.x - (NBLK + 256)) * 256u + tid;
    const unsigned row = gid >> 6, c = (gid & 63) * 4;
    float4 v = *(const float4*)(x + (size_t)row * 256 + c);
    unsigned short h0 = f2bf(v.x), h1 = f2bf(v.y), h2 = f2bf(v.z), h3 = f2bf(v.w);
    float l0 = v.x - __uint_as_float((unsigned)h0 << 16);
    float l1 = v.y - __uint_as_float((unsigned)h1 << 16);
    float l2 = v.z - __uint_as_float((unsigned)h2 << 16);
    float l3 = v.w - __uint_as_float((unsigned)h3 << 16);
    *(ushort4*)(Xsp + (size_t)row * 512 + c) = make_ushort4(h0, h1, h2, h3);
    *(ushort4*)(Xsp + (size_t)row * 512 + 256 + c) =
        make_ushort4(f2bf(l0), f2bf(l1), f2bf(l2), f2bf(l3));
    return;
  }
  if (blockIdx.x >= NBLK) {
    // ---- weight transpose/convert: fp32 [k][n] -> bf16 [n][k] ----
    const int k = blockIdx.x - NBLK;
    float w1 = (tid < 128) ? W_f[k * 128 + tid] : W_b[k * 128 + (tid - 128)];
    Bt1[(size_t)tid * 256 + k] = f2bf(w1);
    Bt2[(size_t)tid * 256 + k] = f2bf(W_fu[k * 256 + tid]);
    return;
  }
  // ---- per-block bucket histograms ----
  __shared__ int hist[2 * NBUCK];
  const int blk = blockIdx.x;
  for (int i = tid; i < 2 * NBUCK; i += 256) hist[i] = 0;
  __syncthreads();
  const int e0 = blk * CHUNK;
  for (int e = e0 + tid; e < e0 + CHUNK; e += 256) {
    int s = ei[e];
    int d = ei[N_EDGES + e];
    atomicAdd(&hist[d >> BSH], 1);
    atomicAdd(&hist[NBUCK + (s >> BSH)], 1);
  }
  __syncthreads();
  for (int i = tid; i < 2 * NBUCK; i += 256)
    blockhist[i * NBLK + blk] = hist[i];
}

// ---------------- per-bucket scan over blocks ----------------
__global__ __launch_bounds__(256) void k_rowscan(const int* __restrict__ blockhist,
                                                 int* __restrict__ blockoffs, int* __restrict__ bucktotal) {
  const int i = blockIdx.x;
  const int t = threadIdx.x;
  __shared__ int s[256];
  int v = (t < NBLK) ? blockhist[i * NBLK + t] : 0;
  s[t] = v;
  __syncthreads();
  for (int off = 1; off < 256; off <<= 1) {
    int u = (t >= off) ? s[t - off] : 0;
    __syncthreads();
    s[t] += u;
    __syncthreads();
  }
  if (t < NBLK) blockoffs[i * NBLK + t] = s[t] - v;
  if (t == 255) bucktotal[i] = s[255];
}

// ---------------- scan bucket totals ----------------
__global__ __launch_bounds__(256) void k_buckscan(const int* __restrict__ bucktotal,
                                                  int* __restrict__ buckbase, int* rpf, int* rpb) {
  __shared__ int s[256];
  const int t = threadIdx.x;
  int v = (t < 2 * NBUCK) ? bucktotal[t] : 0;
  s[t] = v;
  __syncthreads();
  for (int off = 1; off < 256; off <<= 1) {
    int u = (t >= off) ? s[t - off] : 0;
    __syncthreads();
    s[t] += u;
    __syncthreads();
  }
  if (t < 2 * NBUCK) {
    const int dir = (t >= NBUCK) ? 1 : 0;
    const int b = t - dir * NBUCK;
    const int sub = dir ? s[NBUCK - 1] : 0;
    buckbase[dir * (NBUCK + 1) + b] = s[t] - v - sub;
    if (b == NBUCK - 1) buckbase[dir * (NBUCK + 1) + NBUCK] = s[t] - sub;
  }
  if (t == 0) { rpf[N_NODES] = N_EDGES + N_NODES; rpb[N_NODES] = N_EDGES + N_NODES; }
}

// ---------------- scatter edges into bucket-contiguous staging ----------------
__global__ __launch_bounds__(256) void k_stage(const int* __restrict__ ei,
                                               const int* __restrict__ blockoffs,
                                               const int* __restrict__ buckbase,
                                               uint2* __restrict__ staging) {
  __shared__ int cur[2 * NBUCK];
  const int blk = blockIdx.x, tid = threadIdx.x;
  for (int i = tid; i < 2 * NBUCK; i += 256) {
    int dir = (i >= NBUCK) ? 1 : 0;
    int b = i - dir * NBUCK;
    cur[i] = blockoffs[i * NBLK + blk] + buckbase[dir * (NBUCK + 1) + b];
  }
  __syncthreads();
  uint2* st0 = staging;
  uint2* st1 = staging + N_EDGES;
  const int e0 = blk * CHUNK;
  for (int e = e0 + tid; e < e0 + CHUNK; e += 256) {
    int s = ei[e];
    int d = ei[N_EDGES + e];
    int p = atomicAdd(&cur[d >> BSH], 1);
    st0[p] = make_uint2((unsigned)d, (unsigned)s);
    int q = atomicAdd(&cur[NBUCK + (s >> BSH)], 1);
    st1[q] = make_uint2((unsigned)s, (unsigned)d);
  }
}

// ---------------- bin within bucket -> rowptr + adjacency (512 thr, shfl scan) ----------------
__global__ __launch_bounds__(512) void k_bin(const uint2* __restrict__ staging,
                                             const int* __restrict__ buckbase,
                                             int* __restrict__ rpf, int* __restrict__ rpb,
                                             int* __restrict__ adjf, int* __restrict__ adjb) {
  const int b = blockIdx.x, dir = blockIdx.y, tid = threadIdx.x;
  const int node0 = b << BSH;
  const int nn = min(NPB, N_NODES - node0);
  const uint2* st = staging + (size_t)dir * N_EDGES;
  int* rp  = dir ? rpb : rpf;
  int* adj = dir ? adjb : adjf;
  const int beg = buckbase[dir * (NBUCK + 1) + b];
  const int end = buckbase[dir * (NBUCK + 1) + b + 1];

  __shared__ int cnt[NPB];
  __shared__ int wpart[8];
  cnt[tid] = 0;
  __syncthreads();
  for (int jj = beg + tid; jj < end; jj += 512)
    atomicAdd(&cnt[st[jj].x - node0], 1);
  __syncthreads();
  const int deg1 = (tid < nn) ? cnt[tid] + 1 : 0;   // +1 self loop
  int v = deg1;
  const int wl = tid & 63;
#pragma unroll
  for (int off = 1; off < 64; off <<= 1) {
    int u = __shfl_up(v, off, 64);
    if (wl >= off) v += u;
  }
  if (wl == 63) wpart[tid >> 6] = v;
  __syncthreads();
  int pre = 0;
#pragma unroll
  for (int w = 0; w < 7; ++w)
    if (w < (tid >> 6)) pre += wpart[w];
  const int excl = v + pre - deg1;                  // exclusive scan of deg1
  if (tid < nn) {
    int r = beg + node0 + excl;
    rp[node0 + tid] = r;
    adj[r] = node0 + tid;                           // self loop first
    cnt[tid] = r + 1;
  }
  __syncthreads();
  for (int jj = beg + tid; jj < end; jj += 512) {
    uint2 kv = st[jj];
    int p = atomicAdd(&cnt[kv.x - node0], 1);
    adj[p] = (int)kv.y;
  }
}

// ---------------- MFMA GEMM: bf16 [M][512] @ bf16 [512'][256] (B repeats k&255) ----------------
// mode 0: bf16 store split per dir (D0 = fwd cols 0-127, D1 = bwd cols 128-255), ld 128
// mode 1: +bias, BN, ReLU, fp32 [M][256]
#define LDA 40

__global__ __launch_bounds__(256) void k_mm(
    const unsigned short* __restrict__ A, int M,
    const unsigned short* __restrict__ Bt,
    unsigned short* __restrict__ D0, unsigned short* __restrict__ D1,
    float* __restrict__ Df, int mode,
    const float* __restrict__ bias, const float* __restrict__ gamma,
    const float* __restrict__ beta, const float* __restrict__ mean,
    const float* __restrict__ var)
{
  __shared__ __align__(16) unsigned short As[128 * LDA];
  __shared__ __align__(16) unsigned short Bs[128 * LDA];
  const int tid = threadIdx.x;
  const int m0 = blockIdx.x * 128, col0 = blockIdx.y * 128;
  const int wave = tid >> 6, lane = tid & 63;
  const int wm = wave >> 1, wn = wave & 1;
  const int lm = lane & 15, quad = lane >> 4;

  floatx4 acc[4][4];
#pragma unroll
  for (int i = 0; i < 4; ++i)
#pragma unroll
    for (int j = 0; j < 4; ++j) acc[i][j] = (floatx4){0.f, 0.f, 0.f, 0.f};

  for (int it = 0; it < 16; ++it) {
    const int kk0 = it * 32;
    const int kbase = kk0 & 255;
    __syncthreads();
#pragma unroll
    for (int q = 0; q < 2; ++q) {
      int idx = q * 256 + tid;
      int r = idx >> 2, c8 = (idx & 3) * 8;
      ulonglong2 z; z.x = 0; z.y = 0;
      if (m0 + r < M) z = *(const ulonglong2*)(A + (size_t)(m0 + r) * 512 + kk0 + c8);
      *(ulonglong2*)&As[r * LDA + c8] = z;
    }
#pragma unroll
    for (int q = 0; q < 2; ++q) {
      int idx = q * 256 + tid;
      int nc = idx >> 2, c8 = (idx & 3) * 8;
      ulonglong2 z = *(const ulonglong2*)(Bt + (size_t)(col0 + nc) * 256 + kbase + c8);
      *(ulonglong2*)&Bs[nc * LDA + c8] = z;
    }
    __syncthreads();
    short8 a[4], b[4];
#pragma unroll
    for (int i = 0; i < 4; ++i)
      a[i] = *(const short8*)&As[(wm * 64 + i * 16 + lm) * LDA + quad * 8];
#pragma unroll
    for (int j = 0; j < 4; ++j)
      b[j] = *(const short8*)&Bs[(wn * 64 + j * 16 + lm) * LDA + quad * 8];
#pragma unroll
    for (int i = 0; i < 4; ++i)
#pragma unroll
      for (int j = 0; j < 4; ++j)
        acc[i][j] = __builtin_amdgcn_mfma_f32_16x16x32_bf16(a[i], b[j], acc[i][j], 0, 0, 0);
  }

  if (mode == 0) {
    unsigned short* C = (col0 >= 128) ? D1 : D0;
#pragma unroll
    for (int i = 0; i < 4; ++i) {
#pragma unroll
      for (int j = 0; j < 4; ++j) {
        int lc = (wn * 64 + j * 16 + lm);    // local col 0..127 within dir
#pragma unroll
        for (int reg = 0; reg < 4; ++reg) {
          int gr = m0 + wm * 64 + i * 16 + quad * 4 + reg;
          if (gr < M) C[(size_t)gr * 128 + lc] = f2bf(acc[i][j][reg]);
        }
      }
    }
  } else {
#pragma unroll
    for (int j = 0; j < 4; ++j) {
      int gc = col0 + wn * 64 + j * 16 + lm;
      float bi = bias[gc], mu = mean[gc], iv = rsqrtf(var[gc] + 1e-5f);
      float ga = gamma[gc], be = beta[gc];
#pragma unroll
      for (int i = 0; i < 4; ++i) {
#pragma unroll
        for (int reg = 0; reg < 4; ++reg) {
          int gr = m0 + wm * 64 + i * 16 + quad * 4 + reg;
          if (gr < M) {
            float v = acc[i][j][reg] + bi;
            v = (v - mu) * iv * ga + be;
            Df[(size_t)gr * 256 + gc] = fmaxf(v, 0.f);
          }
        }
      }
    }
  }
}

// ---------------- per-node attention score dots (4 nodes/block) ----------------
__global__ __launch_bounds__(256) void k_scores(
    const unsigned short* __restrict__ Xf, const unsigned short* __restrict__ Xb,
    const float* __restrict__ asf, const float* __restrict__ adf,
    const float* __restrict__ asb, const float* __restrict__ adb,
    float* __restrict__ ALf, float* __restrict__ ARf,
    float* __restrict__ ALb, float* __restrict__ ARb)
{
  const int wave = threadIdx.x >> 6, lane = threadIdx.x & 63;
  const int n = blockIdx.x * 4 + wave;
  const int hh = lane >> 5;
  const int c = lane & 31;
  float v0 = bflo((unsigned)Xf[(size_t)n * 128 + lane]);
  float v1 = bflo((unsigned)Xf[(size_t)n * 128 + 64 + lane]);
  float v2 = bflo((unsigned)Xb[(size_t)n * 128 + lane]);
  float v3 = bflo((unsigned)Xb[(size_t)n * 128 + 64 + lane]);
  float s0 = v0 * asf[hh * 32 + c],       d0 = v0 * adf[hh * 32 + c];
  float s1 = v1 * asf[(2 + hh) * 32 + c], d1 = v1 * adf[(2 + hh) * 32 + c];
  float s2 = v2 * asb[hh * 32 + c],       d2 = v2 * adb[hh * 32 + c];
  float s3 = v3 * asb[(2 + hh) * 32 + c], d3 = v3 * adb[(2 + hh) * 32 + c];
#pragma unroll
  for (int off = 16; off > 0; off >>= 1) {
    s0 += __shfl_xor(s0, off, 32); d0 += __shfl_xor(d0, off, 32);
    s1 += __shfl_xor(s1, off, 32); d1 += __shfl_xor(d1, off, 32);
    s2 += __shfl_xor(s2, off, 32); d2 += __shfl_xor(d2, off, 32);
    s3 += __shfl_xor(s3, off, 32); d3 += __shfl_xor(d3, off, 32);
  }
  if (c == 0) {
    ALf[n * 4 + hh] = s0;     ARf[n * 4 + hh] = d0;
    ALf[n * 4 + 2 + hh] = s1; ARf[n * 4 + 2 + hh] = d1;
    ALb[n * 4 + hh] = s2;     ARb[n * 4 + hh] = d2;
    ALb[n * 4 + 2 + hh] = s3; ARb[n * 4 + 2 + hh] = d3;
  }
}

// ---------------- fused softmax + aggregation: 2 edges per wave, 4 nodes/block ----------------
__global__ __launch_bounds__(256) void k_agg(
    const uint2* __restrict__ Xf, const uint2* __restrict__ Xb,
    const int* __restrict__ rpf, const int* __restrict__ adjf,
    const int* __restrict__ rpb, const int* __restrict__ adjb,
    const float* __restrict__ ALf, const float* __restrict__ ARf,
    const float* __restrict__ ALb, const float* __restrict__ ARb,
    const float* __restrict__ bf, const float* __restrict__ bb,
    unsigned* __restrict__ Hsp)
{
  const int dir = blockIdx.y;
  const int wave = threadIdx.x >> 6;
  const int n = blockIdx.x * 4 + wave;
  const uint2* X = dir ? Xb : Xf;
  const int* rp  = dir ? rpb : rpf;
  const int* adj = dir ? adjb : adjf;
  const float* AL = dir ? ALb : ALf;
  const float* AR = dir ? ARb : ARf;
  const float* bias = dir ? bb : bf;
  const int lane = threadIdx.x & 63;
  const int sub = lane >> 5;          // which edge of the pair
  const int t = lane & 31;            // dword-pair index: channels 4t..4t+3
  const unsigned h = (unsigned)(t >> 3);  // head (same for both dwords)
  const float arn = AR[((unsigned)n << 2) | h];
  const int beg = rp[n], end = rp[n + 1];
  const int iters = (end - beg + 1) >> 1;
  const int endm1 = end - 1;
  float a0 = 0.f, a1 = 0.f, a2 = 0.f, a3 = 0.f, den = 0.f;
  int j = beg + sub;
#pragma unroll 4
  for (int it = 0; it < iters; ++it, j += 2) {
    int jj = min(j, endm1);
    int nb = adj[jj];
    float al = AL[((unsigned)nb << 2) | h];
    uint2 u = X[(unsigned)nb * 32u + (unsigned)t];
    float e = al + arn;
    e = fmaxf(e, e * NEG_SLOPE);          // leaky_relu as max(e, 0.2e)
    float w = __expf(e);
    w = (j <= endm1) ? w : 0.f;           // tail mask (sub=1, odd count)
    den += w;
    a0 = fmaf(w, bflo(u.x), a0);
    a1 = fmaf(w, bfhi(u.x), a1);
    a2 = fmaf(w, bflo(u.y), a2);
    a3 = fmaf(w, bfhi(u.y), a3);
  }
  a0 += __shfl_xor(a0, 32); a1 += __shfl_xor(a1, 32);
  a2 += __shfl_xor(a2, 32); a3 += __shfl_xor(a3, 32);
  den += __shfl_xor(den, 32);
  if (sub == 0) {
    float inv = 1.f / (den + 1e-16f);
    float4 bv = *(const float4*)(bias + 4 * t);
    float v0 = a0 * inv + bv.x, v1 = a1 * inv + bv.y;
    float v2 = a2 * inv + bv.z, v3 = a3 * inv + bv.w;
    unsigned short h0 = f2bf(v0), h1 = f2bf(v1), h2 = f2bf(v2), h3 = f2bf(v3);
    float l0 = v0 - __uint_as_float((unsigned)h0 << 16);
    float l1 = v1 - __uint_as_float((unsigned)h1 << 16);
    float l2 = v2 - __uint_as_float((unsigned)h2 << 16);
    float l3 = v3 - __uint_as_float((unsigned)h3 << 16);
    uint2 hiw, low;
    hiw.x = ((unsigned)h1 << 16) | h0;
    hiw.y = ((unsigned)h3 << 16) | h2;
    low.x = ((unsigned)f2bf(l1) << 16) | f2bf(l0);
    low.y = ((unsigned)f2bf(l3) << 16) | f2bf(l2);
    unsigned base = (unsigned)n * 256u + (unsigned)dir * 64u + 2u * (unsigned)t;
    *(uint2*)(Hsp + base) = hiw;
    *(uint2*)(Hsp + base + 128u) = low;
  }
}

// ---------------- launch ----------------

extern "C" void kernel_launch(void* const* d_in, const int* in_sizes, int n_in,
                              void* d_out, int out_size, void* d_ws, size_t ws_size,
                              hipStream_t stream) {
  const float* x    = (const float*)d_in[0];
  const int*   ei   = (const int*)d_in[1];
  const float* W_f  = (const float*)d_in[2];
  const float* asf  = (const float*)d_in[3];
  const float* adf  = (const float*)d_in[4];
  const float* b_f  = (const float*)d_in[5];
  const float* W_b  = (const float*)d_in[6];
  const float* asb  = (const float*)d_in[7];
  const float* adb  = (const float*)d_in[8];
  const float* b_b  = (const float*)d_in[9];
  const float* W_fu = (const float*)d_in[10];
  const float* b_fu = (const float*)d_in[11];
  const float* gam  = (const float*)d_in[12];
  const float* bet  = (const float*)d_in[13];
  const float* mean = (const float*)d_in[14];
  const float* var  = (const float*)d_in[15];
  float* out = (float*)d_out;

  char* base = (char*)d_ws;
  size_t off = 0;
  auto alloc = [&](size_t bytes) {
    void* p = base + off;
    off = (off + bytes + 255) & ~(size_t)255;
    return p;
  };
  // Xsp (mm1 input) and Hsp (mm2 input) are live at disjoint times -> share one region
  unsigned* Hsp          = (unsigned*)alloc((size_t)N_NODES * 256 * 4);   // [N][512] bf16 hi|lo
  unsigned short* Xsp    = (unsigned short*)Hsp;
  unsigned short* Xf     = (unsigned short*)alloc((size_t)N_NODES * 128 * 2);
  unsigned short* Xb     = (unsigned short*)alloc((size_t)N_NODES * 128 * 2);
  unsigned short* Bt1    = (unsigned short*)alloc((size_t)256 * 256 * 2);
  unsigned short* Bt2    = (unsigned short*)alloc((size_t)256 * 256 * 2);
  float* ALf  = (float*)alloc((size_t)N_NODES * 4 * 4);
  float* ARf  = (float*)alloc((size_t)N_NODES * 4 * 4);
  float* ALb  = (float*)alloc((size_t)N_NODES * 4 * 4);
  float* ARb  = (float*)alloc((size_t)N_NODES * 4 * 4);
  int* rpf    = (int*)alloc((size_t)(N_NODES + 1) * 4);
  int* rpb    = (int*)alloc((size_t)(N_NODES + 1) * 4);
  int* adjf   = (int*)alloc((size_t)(N_EDGES + N_NODES) * 4);
  int* adjb   = (int*)alloc((size_t)(N_EDGES + N_NODES) * 4);
  int* blockhist = (int*)alloc((size_t)2 * NBUCK * NBLK * 4);
  int* blockoffs = (int*)alloc((size_t)2 * NBUCK * NBLK * 4);
  int* bucktotal = (int*)alloc((size_t)2 * NBUCK * 4);
  int* buckbase  = (int*)alloc((size_t)2 * (NBUCK + 1) * 4);
  uint2* staging = (uint2*)alloc((size_t)2 * N_EDGES * 8);
  (void)ws_size; (void)in_sizes; (void)n_in; (void)out_size;

  const int SPLITB = (N_NODES * 64) / 256;            // 12500
  k_setup<<<NBLK + 256 + SPLITB, 256, 0, stream>>>(ei, blockhist, W_f, W_b, W_fu,
                                                   Bt1, Bt2, x, Xsp);
  k_rowscan<<<2 * NBUCK, 256, 0, stream>>>(blockhist, blockoffs, bucktotal);
  k_buckscan<<<1, 256, 0, stream>>>(bucktotal, buckbase, rpf, rpb);
  k_stage<<<NBLK, 256, 0, stream>>>(ei, blockoffs, buckbase, staging);
  k_bin<<<dim3(NBUCK, 2), 512, 0, stream>>>(staging, buckbase, rpf, rpb, adjf, adjb);

  const int MB = (N_NODES + 127) / 128;  // 391
  k_mm<<<dim3(MB, 2), 256, 0, stream>>>(Xsp, N_NODES, Bt1, Xf, Xb, nullptr, 0,
                                        nullptr, nullptr, nullptr, nullptr, nullptr);
  k_scores<<<N_NODES / 4, 256, 0, stream>>>(Xf, Xb, asf, adf, asb, adb,
                                            ALf, ARf, ALb, ARb);
  k_agg<<<dim3(N_NODES / 4, 2), 256, 0, stream>>>((const uint2*)Xf, (const uint2*)Xb,
                                                  rpf, adjf, rpb, adjb,
                                                  ALf, ARf, ALb, ARb, b_f, b_b, Hsp);
  k_mm<<<dim3(MB, 2), 256, 0, stream>>>((const unsigned short*)Hsp, N_NODES, Bt2,
                                        nullptr, nullptr, out, 1,
                                        b_fu, gam, bet, mean, var);
}

// Round 6
// 383.138 us; speedup vs baseline: 2.6212x; 1.1225x over previous
//
#include <hip/hip_runtime.h>

#define N_NODES 50000
#define N_EDGES 1600000
#define NEG_SLOPE 0.2f
#define LOG2E 1.44269504f

// CSR build parameters: pow2 node buckets
#define NBUCK 98          // ceil(50000/512)
#define BSH 9             // bucket = node >> 9
#define NPB 512
#define CHUNK 6400
#define NBLK 250          // 250*6400 = 1600000

typedef __attribute__((ext_vector_type(8))) short short8;
typedef __attribute__((ext_vector_type(4))) float floatx4;

__device__ __forceinline__ unsigned short f2bf(float f) {
  unsigned u = __float_as_uint(f);
  u += 0x7FFFu + ((u >> 16) & 1);
  return (unsigned short)(u >> 16);
}
__device__ __forceinline__ float bflo(unsigned u) { return __uint_as_float(u << 16); }
__device__ __forceinline__ float bfhi(unsigned u) { return __uint_as_float(u & 0xFFFF0000u); }

// ---------------- setup: edge histograms + weight prep + x -> bf16 ----------------
__global__ __launch_bounds__(256) void k_setup(
    const int* __restrict__ ei, int* __restrict__ blockhist,
    const float* __restrict__ W_f, const float* __restrict__ W_b,
    const float* __restrict__ W_fu,
    unsigned short* __restrict__ Bt1, unsigned short* __restrict__ Bt2,
    const float* __restrict__ x, unsigned short* __restrict__ Xb16)
{
  const int tid = threadIdx.x;
  if (blockIdx.x >= NBLK + 256) {
    // ---- convert x to bf16 [N][256] ----
    const unsigned gid = (unsigned)(blockIdx.x - (NBLK + 256)) * 256u + tid;
    const unsigned row = gid >> 6, c = (gid & 63) * 4;
    float4 v = *(const float4*)(x + (size_t)row * 256 + c);
    *(ushort4*)(Xb16 + (size_t)row * 256 + c) =
        make_ushort4(f2bf(v.x), f2bf(v.y), f2bf(v.z), f2bf(v.w));
    return;
  }
  if (blockIdx.x >= NBLK) {
    // ---- weight transpose/convert: fp32 [k][n] -> bf16 [n][k] ----
    const int k = blockIdx.x - NBLK;
    float w1 = (tid < 128) ? W_f[k * 128 + tid] : W_b[k * 128 + (tid - 128)];
    Bt1[(size_t)tid * 256 + k] = f2bf(w1);
    Bt2[(size_t)tid * 256 + k] = f2bf(W_fu[k * 256 + tid]);
    return;
  }
  // ---- per-block bucket histograms ----
  __shared__ int hist[2 * NBUCK];
  const int blk = blockIdx.x;
  for (int i = tid; i < 2 * NBUCK; i += 256) hist[i] = 0;
  __syncthreads();
  const int e0 = blk * CHUNK;
  for (int e = e0 + tid; e < e0 + CHUNK; e += 256) {
    int s = ei[e];
    int d = ei[N_EDGES + e];
    atomicAdd(&hist[d >> BSH], 1);
    atomicAdd(&hist[NBUCK + (s >> BSH)], 1);
  }
  __syncthreads();
  for (int i = tid; i < 2 * NBUCK; i += 256)
    blockhist[i * NBLK + blk] = hist[i];
}

// ---------------- per-bucket scan over blocks ----------------
__global__ __launch_bounds__(256) void k_rowscan(const int* __restrict__ blockhist,
                                                 int* __restrict__ blockoffs, int* __restrict__ bucktotal) {
  const int i = blockIdx.x;
  const int t = threadIdx.x;
  __shared__ int s[256];
  int v = (t < NBLK) ? blockhist[i * NBLK + t] : 0;
  s[t] = v;
  __syncthreads();
  for (int off = 1; off < 256; off <<= 1) {
    int u = (t >= off) ? s[t - off] : 0;
    __syncthreads();
    s[t] += u;
    __syncthreads();
  }
  if (t < NBLK) blockoffs[i * NBLK + t] = s[t] - v;
  if (t == 255) bucktotal[i] = s[255];
}

// ---------------- scan bucket totals ----------------
__global__ __launch_bounds__(256) void k_buckscan(const int* __restrict__ bucktotal,
                                                  int* __restrict__ buckbase, int* rpf, int* rpb) {
  __shared__ int s[256];
  const int t = threadIdx.x;
  int v = (t < 2 * NBUCK) ? bucktotal[t] : 0;
  s[t] = v;
  __syncthreads();
  for (int off = 1; off < 256; off <<= 1) {
    int u = (t >= off) ? s[t - off] : 0;
    __syncthreads();
    s[t] += u;
    __syncthreads();
  }
  if (t < 2 * NBUCK) {
    const int dir = (t >= NBUCK) ? 1 : 0;
    const int b = t - dir * NBUCK;
    const int sub = dir ? s[NBUCK - 1] : 0;
    buckbase[dir * (NBUCK + 1) + b] = s[t] - v - sub;
    if (b == NBUCK - 1) buckbase[dir * (NBUCK + 1) + NBUCK] = s[t] - sub;
  }
  if (t == 0) { rpf[N_NODES] = N_EDGES + N_NODES; rpb[N_NODES] = N_EDGES + N_NODES; }
}

// ---------------- scatter edges into bucket-contiguous staging (packed 4B) ----------------
// record = (local_dst_key << 16) | neighbor_id   (N_NODES < 65536)
__global__ __launch_bounds__(256) void k_stage(const int* __restrict__ ei,
                                               const int* __restrict__ blockoffs,
                                               const int* __restrict__ buckbase,
                                               unsigned* __restrict__ staging) {
  __shared__ int cur[2 * NBUCK];
  const int blk = blockIdx.x, tid = threadIdx.x;
  for (int i = tid; i < 2 * NBUCK; i += 256) {
    int dir = (i >= NBUCK) ? 1 : 0;
    int b = i - dir * NBUCK;
    cur[i] = blockoffs[i * NBLK + blk] + buckbase[dir * (NBUCK + 1) + b];
  }
  __syncthreads();
  unsigned* st0 = staging;
  unsigned* st1 = staging + N_EDGES;
  const int e0 = blk * CHUNK;
  for (int e = e0 + tid; e < e0 + CHUNK; e += 256) {
    int s = ei[e];
    int d = ei[N_EDGES + e];
    int p = atomicAdd(&cur[d >> BSH], 1);
    st0[p] = ((unsigned)(d & (NPB - 1)) << 16) | (unsigned)s;
    int q = atomicAdd(&cur[NBUCK + (s >> BSH)], 1);
    st1[q] = ((unsigned)(s & (NPB - 1)) << 16) | (unsigned)d;
  }
}

// ---------------- bin within bucket -> rowptr + adjacency ----------------
__global__ __launch_bounds__(512) void k_bin(const unsigned* __restrict__ staging,
                                             const int* __restrict__ buckbase,
                                             int* __restrict__ rpf, int* __restrict__ rpb,
                                             int* __restrict__ adjf, int* __restrict__ adjb) {
  const int b = blockIdx.x, dir = blockIdx.y, tid = threadIdx.x;
  const int node0 = b << BSH;
  const int nn = min(NPB, N_NODES - node0);
  const unsigned* st = staging + (size_t)dir * N_EDGES;
  int* rp  = dir ? rpb : rpf;
  int* adj = dir ? adjb : adjf;
  const int beg = buckbase[dir * (NBUCK + 1) + b];
  const int end = buckbase[dir * (NBUCK + 1) + b + 1];

  __shared__ int cnt[NPB];
  __shared__ int wpart[8];
  cnt[tid] = 0;
  __syncthreads();
  for (int jj = beg + tid; jj < end; jj += 512)
    atomicAdd(&cnt[st[jj] >> 16], 1);
  __syncthreads();
  const int deg1 = (tid < nn) ? cnt[tid] + 1 : 0;   // +1 self loop
  int v = deg1;
  const int wl = tid & 63;
#pragma unroll
  for (int off = 1; off < 64; off <<= 1) {
    int u = __shfl_up(v, off, 64);
    if (wl >= off) v += u;
  }
  if (wl == 63) wpart[tid >> 6] = v;
  __syncthreads();
  int pre = 0;
#pragma unroll
  for (int w = 0; w < 7; ++w)
    if (w < (tid >> 6)) pre += wpart[w];
  const int excl = v + pre - deg1;
  if (tid < nn) {
    int r = beg + node0 + excl;
    rp[node0 + tid] = r;
    adj[r] = node0 + tid;                           // self loop first
    cnt[tid] = r + 1;
  }
  __syncthreads();
  for (int jj = beg + tid; jj < end; jj += 512) {
    unsigned rec = st[jj];
    int p = atomicAdd(&cnt[rec >> 16], 1);
    adj[p] = (int)(rec & 0xFFFFu);
  }
}

// ---------------- MFMA GEMM: bf16 [M][256] @ bf16 [256 x 256] ----------------
// mode 0: bf16 store split per dir (D0 = fwd cols 0-127, D1 = bwd cols 128-255), ld 128
// mode 1: +bias, BN, ReLU, fp32 [M][256]
#define LDA 40

__global__ __launch_bounds__(256) void k_mm(
    const unsigned short* __restrict__ A, int M,
    const unsigned short* __restrict__ Bt,
    unsigned short* __restrict__ D0, unsigned short* __restrict__ D1,
    float* __restrict__ Df, int mode,
    const float* __restrict__ bias, const float* __restrict__ gamma,
    const float* __restrict__ beta, const float* __restrict__ mean,
    const float* __restrict__ var)
{
  __shared__ __align__(16) unsigned short As[128 * LDA];
  __shared__ __align__(16) unsigned short Bs[128 * LDA];
  const int tid = threadIdx.x;
  const int m0 = blockIdx.x * 128, col0 = blockIdx.y * 128;
  const int wave = tid >> 6, lane = tid & 63;
  const int wm = wave >> 1, wn = wave & 1;
  const int lm = lane & 15, quad = lane >> 4;

  floatx4 acc[4][4];
#pragma unroll
  for (int i = 0; i < 4; ++i)
#pragma unroll
    for (int j = 0; j < 4; ++j) acc[i][j] = (floatx4){0.f, 0.f, 0.f, 0.f};

  for (int it = 0; it < 8; ++it) {
    const int kk0 = it * 32;
    __syncthreads();
#pragma unroll
    for (int q = 0; q < 2; ++q) {
      int idx = q * 256 + tid;
      int r = idx >> 2, c8 = (idx & 3) * 8;
      ulonglong2 z; z.x = 0; z.y = 0;
      if (m0 + r < M) z = *(const ulonglong2*)(A + (size_t)(m0 + r) * 256 + kk0 + c8);
      *(ulonglong2*)&As[r * LDA + c8] = z;
    }
#pragma unroll
    for (int q = 0; q < 2; ++q) {
      int idx = q * 256 + tid;
      int nc = idx >> 2, c8 = (idx & 3) * 8;
      ulonglong2 z = *(const ulonglong2*)(Bt + (size_t)(col0 + nc) * 256 + kk0 + c8);
      *(ulonglong2*)&Bs[nc * LDA + c8] = z;
    }
    __syncthreads();
    short8 a[4], b[4];
#pragma unroll
    for (int i = 0; i < 4; ++i)
      a[i] = *(const short8*)&As[(wm * 64 + i * 16 + lm) * LDA + quad * 8];
#pragma unroll
    for (int j = 0; j < 4; ++j)
      b[j] = *(const short8*)&Bs[(wn * 64 + j * 16 + lm) * LDA + quad * 8];
#pragma unroll
    for (int i = 0; i < 4; ++i)
#pragma unroll
      for (int j = 0; j < 4; ++j)
        acc[i][j] = __builtin_amdgcn_mfma_f32_16x16x32_bf16(a[i], b[j], acc[i][j], 0, 0, 0);
  }

  if (mode == 0) {
    unsigned short* C = (col0 >= 128) ? D1 : D0;
#pragma unroll
    for (int i = 0; i < 4; ++i) {
#pragma unroll
      for (int j = 0; j < 4; ++j) {
        int lc = (wn * 64 + j * 16 + lm);
#pragma unroll
        for (int reg = 0; reg < 4; ++reg) {
          int gr = m0 + wm * 64 + i * 16 + quad * 4 + reg;
          if (gr < M) C[(size_t)gr * 128 + lc] = f2bf(acc[i][j][reg]);
        }
      }
    }
  } else {
#pragma unroll
    for (int j = 0; j < 4; ++j) {
      int gc = col0 + wn * 64 + j * 16 + lm;
      float bi = bias[gc], mu = mean[gc], iv = rsqrtf(var[gc] + 1e-5f);
      float ga = gamma[gc], be = beta[gc];
#pragma unroll
      for (int i = 0; i < 4; ++i) {
#pragma unroll
        for (int reg = 0; reg < 4; ++reg) {
          int gr = m0 + wm * 64 + i * 16 + quad * 4 + reg;
          if (gr < M) {
            float v = acc[i][j][reg] + bi;
            v = (v - mu) * iv * ga + be;
            Df[(size_t)gr * 256 + gc] = fmaxf(v, 0.f);
          }
        }
      }
    }
  }
}

// ---------------- per-node attention score dots (outputs pre-scaled by log2e) ----------------
__global__ __launch_bounds__(256) void k_scores(
    const unsigned short* __restrict__ Xf, const unsigned short* __restrict__ Xb,
    const float* __restrict__ asf, const float* __restrict__ adf,
    const float* __restrict__ asb, const float* __restrict__ adb,
    float* __restrict__ ALf, float* __restrict__ ARf,
    float* __restrict__ ALb, float* __restrict__ ARb)
{
  const int wave = threadIdx.x >> 6, lane = threadIdx.x & 63;
  const int n = blockIdx.x * 4 + wave;
  const int hh = lane >> 5;
  const int c = lane & 31;
  float v0 = bflo((unsigned)Xf[(size_t)n * 128 + lane]);
  float v1 = bflo((unsigned)Xf[(size_t)n * 128 + 64 + lane]);
  float v2 = bflo((unsigned)Xb[(size_t)n * 128 + lane]);
  float v3 = bflo((unsigned)Xb[(size_t)n * 128 + 64 + lane]);
  float s0 = v0 * asf[hh * 32 + c],       d0 = v0 * adf[hh * 32 + c];
  float s1 = v1 * asf[(2 + hh) * 32 + c], d1 = v1 * adf[(2 + hh) * 32 + c];
  float s2 = v2 * asb[hh * 32 + c],       d2 = v2 * adb[hh * 32 + c];
  float s3 = v3 * asb[(2 + hh) * 32 + c], d3 = v3 * adb[(2 + hh) * 32 + c];
#pragma unroll
  for (int off = 16; off > 0; off >>= 1) {
    s0 += __shfl_xor(s0, off, 32); d0 += __shfl_xor(d0, off, 32);
    s1 += __shfl_xor(s1, off, 32); d1 += __shfl_xor(d1, off, 32);
    s2 += __shfl_xor(s2, off, 32); d2 += __shfl_xor(d2, off, 32);
    s3 += __shfl_xor(s3, off, 32); d3 += __shfl_xor(d3, off, 32);
  }
  if (c == 0) {
    ALf[n * 4 + hh] = s0 * LOG2E;     ARf[n * 4 + hh] = d0 * LOG2E;
    ALf[n * 4 + 2 + hh] = s1 * LOG2E; ARf[n * 4 + 2 + hh] = d1 * LOG2E;
    ALb[n * 4 + hh] = s2 * LOG2E;     ARb[n * 4 + hh] = d2 * LOG2E;
    ALb[n * 4 + 2 + hh] = s3 * LOG2E; ARb[n * 4 + 2 + hh] = d3 * LOG2E;
  }
}

// ---------------- fused softmax + aggregation: 2 edges per wave ----------------
// AL/AR pre-scaled by log2e -> exp2f; tail hoisted out of main loop.
__global__ __launch_bounds__(256) void k_agg(
    const uint2* __restrict__ Xf, const uint2* __restrict__ Xb,
    const int* __restrict__ rpf, const int* __restrict__ adjf,
    const int* __restrict__ rpb, const int* __restrict__ adjb,
    const float* __restrict__ ALf, const float* __restrict__ ARf,
    const float* __restrict__ ALb, const float* __restrict__ ARb,
    const float* __restrict__ bf, const float* __restrict__ bb,
    unsigned* __restrict__ H16)
{
  const int dir = blockIdx.y;
  const int wave = threadIdx.x >> 6;
  const int n = blockIdx.x * 4 + wave;
  const uint2* X = dir ? Xb : Xf;
  const int* rp  = dir ? rpb : rpf;
  const int* adj = dir ? adjb : adjf;
  const float* AL = dir ? ALb : ALf;
  const float* AR = dir ? ARb : ARf;
  const float* bias = dir ? bb : bf;
  const int lane = threadIdx.x & 63;
  const int sub = lane >> 5;
  const unsigned t = (unsigned)(lane & 31);
  const unsigned h = t >> 3;
  const float arn = AR[((unsigned)n << 2) | h];
  const int beg = rp[n], end = rp[n + 1];
  const int cntE = end - beg;
  const int full = cntE >> 1;
  float a0 = 0.f, a1 = 0.f, a2 = 0.f, a3 = 0.f, den = 0.f;
  const int* ap = adj + beg + sub;
#pragma unroll 4
  for (int it = 0; it < full; ++it, ap += 2) {
    int nb = *ap;
    float al = AL[((unsigned)nb << 2) | h];
    uint2 u = X[((unsigned)nb << 5) | t];
    float s = al + arn;
    float e = fmaxf(s, s * NEG_SLOPE);
    float w = exp2f(e);
    den += w;
    a0 = fmaf(w, bflo(u.x), a0);
    a1 = fmaf(w, bfhi(u.x), a1);
    a2 = fmaf(w, bflo(u.y), a2);
    a3 = fmaf(w, bfhi(u.y), a3);
  }
  if (cntE & 1) {   // wave-uniform branch
    int nb = adj[end - 1];
    float al = AL[((unsigned)nb << 2) | h];
    uint2 u = X[((unsigned)nb << 5) | t];
    float s = al + arn;
    float e = fmaxf(s, s * NEG_SLOPE);
    float w = exp2f(e);
    w = (sub == 0) ? w : 0.f;
    den += w;
    a0 = fmaf(w, bflo(u.x), a0);
    a1 = fmaf(w, bfhi(u.x), a1);
    a2 = fmaf(w, bflo(u.y), a2);
    a3 = fmaf(w, bfhi(u.y), a3);
  }
  a0 += __shfl_xor(a0, 32); a1 += __shfl_xor(a1, 32);
  a2 += __shfl_xor(a2, 32); a3 += __shfl_xor(a3, 32);
  den += __shfl_xor(den, 32);
  if (sub == 0) {
    float inv = 1.f / (den + 1e-16f);
    float4 bv = *(const float4*)(bias + 4 * t);
    float v0 = a0 * inv + bv.x, v1 = a1 * inv + bv.y;
    float v2 = a2 * inv + bv.z, v3 = a3 * inv + bv.w;
    uint2 hw;
    hw.x = ((unsigned)f2bf(v1) << 16) | f2bf(v0);
    hw.y = ((unsigned)f2bf(v3) << 16) | f2bf(v2);
    unsigned base = (unsigned)n * 128u + (unsigned)dir * 64u + 2u * t;
    *(uint2*)(H16 + base) = hw;
  }
}

// ---------------- launch ----------------

extern "C" void kernel_launch(void* const* d_in, const int* in_sizes, int n_in,
                              void* d_out, int out_size, void* d_ws, size_t ws_size,
                              hipStream_t stream) {
  const float* x    = (const float*)d_in[0];
  const int*   ei   = (const int*)d_in[1];
  const float* W_f  = (const float*)d_in[2];
  const float* asf  = (const float*)d_in[3];
  const float* adf  = (const float*)d_in[4];
  const float* b_f  = (const float*)d_in[5];
  const float* W_b  = (const float*)d_in[6];
  const float* asb  = (const float*)d_in[7];
  const float* adb  = (const float*)d_in[8];
  const float* b_b  = (const float*)d_in[9];
  const float* W_fu = (const float*)d_in[10];
  const float* b_fu = (const float*)d_in[11];
  const float* gam  = (const float*)d_in[12];
  const float* bet  = (const float*)d_in[13];
  const float* mean = (const float*)d_in[14];
  const float* var  = (const float*)d_in[15];
  float* out = (float*)d_out;

  char* base = (char*)d_ws;
  size_t off = 0;
  auto alloc = [&](size_t bytes) {
    void* p = base + off;
    off = (off + bytes + 255) & ~(size_t)255;
    return p;
  };
  // Xb16 (mm1 input) and H16 (agg output / mm2 input) live at disjoint times -> share
  unsigned short* Xb16 = (unsigned short*)alloc((size_t)N_NODES * 256 * 2);
  unsigned* H16        = (unsigned*)Xb16;
  unsigned short* Xf   = (unsigned short*)alloc((size_t)N_NODES * 128 * 2);
  unsigned short* Xb   = (unsigned short*)alloc((size_t)N_NODES * 128 * 2);
  unsigned short* Bt1  = (unsigned short*)alloc((size_t)256 * 256 * 2);
  unsigned short* Bt2  = (unsigned short*)alloc((size_t)256 * 256 * 2);
  float* ALf  = (float*)alloc((size_t)N_NODES * 4 * 4);
  float* ARf  = (float*)alloc((size_t)N_NODES * 4 * 4);
  float* ALb  = (float*)alloc((size_t)N_NODES * 4 * 4);
  float* ARb  = (float*)alloc((size_t)N_NODES * 4 * 4);
  int* rpf    = (int*)alloc((size_t)(N_NODES + 1) * 4);
  int* rpb    = (int*)alloc((size_t)(N_NODES + 1) * 4);
  int* adjf   = (int*)alloc((size_t)(N_EDGES + N_NODES) * 4);
  int* adjb   = (int*)alloc((size_t)(N_EDGES + N_NODES) * 4);
  int* blockhist = (int*)alloc((size_t)2 * NBUCK * NBLK * 4);
  int* blockoffs = (int*)alloc((size_t)2 * NBUCK * NBLK * 4);
  int* bucktotal = (int*)alloc((size_t)2 * NBUCK * 4);
  int* buckbase  = (int*)alloc((size_t)2 * (NBUCK + 1) * 4);
  unsigned* staging = (unsigned*)alloc((size_t)2 * N_EDGES * 4);
  (void)ws_size; (void)in_sizes; (void)n_in; (void)out_size;

  const int XB = (N_NODES * 64) / 256;            // 12500
  k_setup<<<NBLK + 256 + XB, 256, 0, stream>>>(ei, blockhist, W_f, W_b, W_fu,
                                               Bt1, Bt2, x, Xb16);
  k_rowscan<<<2 * NBUCK, 256, 0, stream>>>(blockhist, blockoffs, bucktotal);
  k_buckscan<<<1, 256, 0, stream>>>(bucktotal, buckbase, rpf, rpb);
  k_stage<<<NBLK, 256, 0, stream>>>(ei, blockoffs, buckbase, staging);
  k_bin<<<dim3(NBUCK, 2), 512, 0, stream>>>(staging, buckbase, rpf, rpb, adjf, adjb);

  const int MB = (N_NODES + 127) / 128;  // 391
  k_mm<<<dim3(MB, 2), 256, 0, stream>>>(Xb16, N_NODES, Bt1, Xf, Xb, nullptr, 0,
                                        nullptr, nullptr, nullptr, nullptr, nullptr);
  k_scores<<<N_NODES / 4, 256, 0, stream>>>(Xf, Xb, asf, adf, asb, adb,
                                            ALf, ARf, ALb, ARb);
  k_agg<<<dim3(N_NODES / 4, 2), 256, 0, stream>>>((const uint2*)Xf, (const uint2*)Xb,
                                                  rpf, adjf, rpb, adjb,
                                                  ALf, ARf, ALb, ARb, b_f, b_b, H16);
  k_mm<<<dim3(MB, 2), 256, 0, stream>>>((const unsigned short*)H16, N_NODES, Bt2,
                                        nullptr, nullptr, out, 1,
                                        b_fu, gam, bet, mean, var);
}

// Round 7
// 350.735 us; speedup vs baseline: 2.8634x; 1.0924x over previous
//
#include <hip/hip_runtime.h>

#define N_NODES 50000
#define N_EDGES 1600000
#define NEG_SLOPE 0.2f
#define LOG2E 1.44269504f

// CSR build parameters: pow2 node buckets
#define NBUCK 98          // ceil(50000/512)
#define BSH 9             // bucket = node >> 9
#define NPB 512
#define CHUNK 6400
#define NBLK 250          // 250*6400 = 1600000

typedef __attribute__((ext_vector_type(8))) short short8;
typedef __attribute__((ext_vector_type(4))) float floatx4;

__device__ __forceinline__ unsigned short f2bf(float f) {
  unsigned u = __float_as_uint(f);
  u += 0x7FFFu + ((u >> 16) & 1);
  return (unsigned short)(u >> 16);
}
__device__ __forceinline__ float bflo(unsigned u) { return __uint_as_float(u << 16); }
__device__ __forceinline__ float bfhi(unsigned u) { return __uint_as_float(u & 0xFFFF0000u); }
__device__ __forceinline__ float fexp2(float x) {
#if __has_builtin(__builtin_amdgcn_exp2f)
  return __builtin_amdgcn_exp2f(x);   // raw v_exp_f32
#else
  return exp2f(x);
#endif
}

// ---------------- setup: edge histograms + weight prep + x -> bf16 ----------------
__global__ __launch_bounds__(256) void k_setup(
    const int* __restrict__ ei, int* __restrict__ blockhist,
    const float* __restrict__ W_f, const float* __restrict__ W_b,
    const float* __restrict__ W_fu,
    unsigned short* __restrict__ Bt1, unsigned short* __restrict__ Bt2,
    const float* __restrict__ x, unsigned short* __restrict__ Xb16)
{
  const int tid = threadIdx.x;
  if (blockIdx.x >= NBLK + 256) {
    const unsigned gid = (unsigned)(blockIdx.x - (NBLK + 256)) * 256u + tid;
    const unsigned row = gid >> 6, c = (gid & 63) * 4;
    float4 v = *(const float4*)(x + (size_t)row * 256 + c);
    *(ushort4*)(Xb16 + (size_t)row * 256 + c) =
        make_ushort4(f2bf(v.x), f2bf(v.y), f2bf(v.z), f2bf(v.w));
    return;
  }
  if (blockIdx.x >= NBLK) {
    const int k = blockIdx.x - NBLK;
    float w1 = (tid < 128) ? W_f[k * 128 + tid] : W_b[k * 128 + (tid - 128)];
    Bt1[(size_t)tid * 256 + k] = f2bf(w1);
    Bt2[(size_t)tid * 256 + k] = f2bf(W_fu[k * 256 + tid]);
    return;
  }
  __shared__ int hist[2 * NBUCK];
  const int blk = blockIdx.x;
  for (int i = tid; i < 2 * NBUCK; i += 256) hist[i] = 0;
  __syncthreads();
  const int e0 = blk * CHUNK;
  for (int e = e0 + tid; e < e0 + CHUNK; e += 256) {
    int s = ei[e];
    int d = ei[N_EDGES + e];
    atomicAdd(&hist[d >> BSH], 1);
    atomicAdd(&hist[NBUCK + (s >> BSH)], 1);
  }
  __syncthreads();
  for (int i = tid; i < 2 * NBUCK; i += 256)
    blockhist[i * NBLK + blk] = hist[i];
}

// ---------------- per-bucket scan over blocks ----------------
__global__ __launch_bounds__(256) void k_rowscan(const int* __restrict__ blockhist,
                                                 int* __restrict__ blockoffs, int* __restrict__ bucktotal) {
  const int i = blockIdx.x;
  const int t = threadIdx.x;
  __shared__ int s[256];
  int v = (t < NBLK) ? blockhist[i * NBLK + t] : 0;
  s[t] = v;
  __syncthreads();
  for (int off = 1; off < 256; off <<= 1) {
    int u = (t >= off) ? s[t - off] : 0;
    __syncthreads();
    s[t] += u;
    __syncthreads();
  }
  if (t < NBLK) blockoffs[i * NBLK + t] = s[t] - v;
  if (t == 255) bucktotal[i] = s[255];
}

// ---------------- scan bucket totals ----------------
__global__ __launch_bounds__(256) void k_buckscan(const int* __restrict__ bucktotal,
                                                  int* __restrict__ buckbase, int* rpf, int* rpb) {
  __shared__ int s[256];
  const int t = threadIdx.x;
  int v = (t < 2 * NBUCK) ? bucktotal[t] : 0;
  s[t] = v;
  __syncthreads();
  for (int off = 1; off < 256; off <<= 1) {
    int u = (t >= off) ? s[t - off] : 0;
    __syncthreads();
    s[t] += u;
    __syncthreads();
  }
  if (t < 2 * NBUCK) {
    const int dir = (t >= NBUCK) ? 1 : 0;
    const int b = t - dir * NBUCK;
    const int sub = dir ? s[NBUCK - 1] : 0;
    buckbase[dir * (NBUCK + 1) + b] = s[t] - v - sub;
    if (b == NBUCK - 1) buckbase[dir * (NBUCK + 1) + NBUCK] = s[t] - sub;
  }
  if (t == 0) { rpf[N_NODES] = N_EDGES + N_NODES; rpb[N_NODES] = N_EDGES + N_NODES; }
}

// ---------------- MFMA GEMM body (shared by fused + standalone kernels) ----------------
#define LDA 40

__device__ __forceinline__ void mm_body(
    const unsigned short* __restrict__ A, int M,
    const unsigned short* __restrict__ Bt,
    unsigned short* __restrict__ D0, unsigned short* __restrict__ D1,
    float* __restrict__ Df, int mode,
    const float* __restrict__ bias, const float* __restrict__ gamma,
    const float* __restrict__ beta, const float* __restrict__ mean,
    const float* __restrict__ var,
    int m0, int col0, unsigned short* As, unsigned short* Bs)
{
  const int tid = threadIdx.x;
  const int wave = tid >> 6, lane = tid & 63;
  const int wm = wave >> 1, wn = wave & 1;
  const int lm = lane & 15, quad = lane >> 4;

  floatx4 acc[4][4];
#pragma unroll
  for (int i = 0; i < 4; ++i)
#pragma unroll
    for (int j = 0; j < 4; ++j) acc[i][j] = (floatx4){0.f, 0.f, 0.f, 0.f};

  for (int it = 0; it < 8; ++it) {
    const int kk0 = it * 32;
    __syncthreads();
#pragma unroll
    for (int q = 0; q < 2; ++q) {
      int idx = q * 256 + tid;
      int r = idx >> 2, c8 = (idx & 3) * 8;
      ulonglong2 z; z.x = 0; z.y = 0;
      if (m0 + r < M) z = *(const ulonglong2*)(A + (size_t)(m0 + r) * 256 + kk0 + c8);
      *(ulonglong2*)&As[r * LDA + c8] = z;
    }
#pragma unroll
    for (int q = 0; q < 2; ++q) {
      int idx = q * 256 + tid;
      int nc = idx >> 2, c8 = (idx & 3) * 8;
      ulonglong2 z = *(const ulonglong2*)(Bt + (size_t)(col0 + nc) * 256 + kk0 + c8);
      *(ulonglong2*)&Bs[nc * LDA + c8] = z;
    }
    __syncthreads();
    short8 a[4], b[4];
#pragma unroll
    for (int i = 0; i < 4; ++i)
      a[i] = *(const short8*)&As[(wm * 64 + i * 16 + lm) * LDA + quad * 8];
#pragma unroll
    for (int j = 0; j < 4; ++j)
      b[j] = *(const short8*)&Bs[(wn * 64 + j * 16 + lm) * LDA + quad * 8];
#pragma unroll
    for (int i = 0; i < 4; ++i)
#pragma unroll
      for (int j = 0; j < 4; ++j)
        acc[i][j] = __builtin_amdgcn_mfma_f32_16x16x32_bf16(a[i], b[j], acc[i][j], 0, 0, 0);
  }

  if (mode == 0) {
    unsigned short* C = (col0 >= 128) ? D1 : D0;
#pragma unroll
    for (int i = 0; i < 4; ++i) {
#pragma unroll
      for (int j = 0; j < 4; ++j) {
        int lc = (wn * 64 + j * 16 + lm);
#pragma unroll
        for (int reg = 0; reg < 4; ++reg) {
          int gr = m0 + wm * 64 + i * 16 + quad * 4 + reg;
          if (gr < M) C[(size_t)gr * 128 + lc] = f2bf(acc[i][j][reg]);
        }
      }
    }
  } else {
#pragma unroll
    for (int j = 0; j < 4; ++j) {
      int gc = col0 + wn * 64 + j * 16 + lm;
      float bi = bias[gc], mu = mean[gc], iv = rsqrtf(var[gc] + 1e-5f);
      float ga = gamma[gc], be = beta[gc];
#pragma unroll
      for (int i = 0; i < 4; ++i) {
#pragma unroll
        for (int reg = 0; reg < 4; ++reg) {
          int gr = m0 + wm * 64 + i * 16 + quad * 4 + reg;
          if (gr < M) {
            float v = acc[i][j][reg] + bi;
            v = (v - mu) * iv * ga + be;
            Df[(size_t)gr * 256 + gc] = fmaxf(v, 0.f);
          }
        }
      }
    }
  }
}

// ---------------- fused: edge scatter-to-staging + projection GEMM ----------------
__global__ __launch_bounds__(256) void k_stage_mm(
    const int* __restrict__ ei, const int* __restrict__ blockoffs,
    const int* __restrict__ buckbase, unsigned* __restrict__ staging,
    const unsigned short* __restrict__ Xb16, const unsigned short* __restrict__ Bt1,
    unsigned short* __restrict__ Xf, unsigned short* __restrict__ Xb)
{
  __shared__ union {
    int cur[2 * NBUCK];
    struct { unsigned short As[128 * LDA]; unsigned short Bs[128 * LDA]; } mm;
  } sm;
  const int tid = threadIdx.x;
  if (blockIdx.x < NBLK) {
    const int blk = blockIdx.x;
    for (int i = tid; i < 2 * NBUCK; i += 256) {
      int dir = (i >= NBUCK) ? 1 : 0;
      int b = i - dir * NBUCK;
      sm.cur[i] = blockoffs[i * NBLK + blk] + buckbase[dir * (NBUCK + 1) + b];
    }
    __syncthreads();
    unsigned* st0 = staging;
    unsigned* st1 = staging + N_EDGES;
    const int e0 = blk * CHUNK;
    for (int e = e0 + tid; e < e0 + CHUNK; e += 256) {
      int s = ei[e];
      int d = ei[N_EDGES + e];
      int p = atomicAdd(&sm.cur[d >> BSH], 1);
      st0[p] = ((unsigned)(d & (NPB - 1)) << 16) | (unsigned)s;
      int q = atomicAdd(&sm.cur[NBUCK + (s >> BSH)], 1);
      st1[q] = ((unsigned)(s & (NPB - 1)) << 16) | (unsigned)d;
    }
    return;
  }
  const int bid = blockIdx.x - NBLK;
  mm_body(Xb16, N_NODES, Bt1, Xf, Xb, nullptr, 0,
          nullptr, nullptr, nullptr, nullptr, nullptr,
          (bid >> 1) * 128, (bid & 1) * 128, sm.mm.As, sm.mm.Bs);
}

// ---------------- fused: bin-within-bucket + attention score dots ----------------
__global__ __launch_bounds__(512) void k_bin_scores(
    const unsigned* __restrict__ staging, const int* __restrict__ buckbase,
    int* __restrict__ rpf, int* __restrict__ rpb,
    int* __restrict__ adjf, int* __restrict__ adjb,
    const unsigned short* __restrict__ Xf, const unsigned short* __restrict__ Xb,
    const float* __restrict__ asf, const float* __restrict__ adf,
    const float* __restrict__ asb, const float* __restrict__ adb,
    float* __restrict__ ALf, float* __restrict__ ARf,
    float* __restrict__ ALb, float* __restrict__ ARb)
{
  const int tid = threadIdx.x;
  if (blockIdx.x < 2 * NBUCK) {
    const int dir = (blockIdx.x >= NBUCK) ? 1 : 0;
    const int b = blockIdx.x - dir * NBUCK;
    const int node0 = b << BSH;
    const int nn = min(NPB, N_NODES - node0);
    const unsigned* st = staging + (size_t)dir * N_EDGES;
    int* rp  = dir ? rpb : rpf;
    int* adj = dir ? adjb : adjf;
    const int beg = buckbase[dir * (NBUCK + 1) + b];
    const int end = buckbase[dir * (NBUCK + 1) + b + 1];

    __shared__ int cnt[NPB];
    __shared__ int wpart[8];
    cnt[tid] = 0;
    __syncthreads();
    for (int jj = beg + tid; jj < end; jj += 512)
      atomicAdd(&cnt[st[jj] >> 16], 1);
    __syncthreads();
    const int deg1 = (tid < nn) ? cnt[tid] + 1 : 0;   // +1 self loop
    int v = deg1;
    const int wl = tid & 63;
#pragma unroll
    for (int off = 1; off < 64; off <<= 1) {
      int u = __shfl_up(v, off, 64);
      if (wl >= off) v += u;
    }
    if (wl == 63) wpart[tid >> 6] = v;
    __syncthreads();
    int pre = 0;
#pragma unroll
    for (int w = 0; w < 7; ++w)
      if (w < (tid >> 6)) pre += wpart[w];
    const int excl = v + pre - deg1;
    if (tid < nn) {
      int r = beg + node0 + excl;
      rp[node0 + tid] = r;
      adj[r] = node0 + tid;                           // self loop first
      cnt[tid] = r + 1;
    }
    __syncthreads();
    for (int jj = beg + tid; jj < end; jj += 512) {
      unsigned rec = st[jj];
      int p = atomicAdd(&cnt[rec >> 16], 1);
      adj[p] = (int)(rec & 0xFFFFu);
    }
    return;
  }
  // ---- scores: 8 nodes per block (one wave each), outputs pre-scaled by log2e ----
  const int wave = tid >> 6, lane = tid & 63;
  const int n = (blockIdx.x - 2 * NBUCK) * 8 + wave;
  const int hh = lane >> 5;
  const int c = lane & 31;
  float v0 = bflo((unsigned)Xf[(size_t)n * 128 + lane]);
  float v1 = bflo((unsigned)Xf[(size_t)n * 128 + 64 + lane]);
  float v2 = bflo((unsigned)Xb[(size_t)n * 128 + lane]);
  float v3 = bflo((unsigned)Xb[(size_t)n * 128 + 64 + lane]);
  float s0 = v0 * asf[hh * 32 + c],       d0 = v0 * adf[hh * 32 + c];
  float s1 = v1 * asf[(2 + hh) * 32 + c], d1 = v1 * adf[(2 + hh) * 32 + c];
  float s2 = v2 * asb[hh * 32 + c],       d2 = v2 * adb[hh * 32 + c];
  float s3 = v3 * asb[(2 + hh) * 32 + c], d3 = v3 * adb[(2 + hh) * 32 + c];
#pragma unroll
  for (int off = 16; off > 0; off >>= 1) {
    s0 += __shfl_xor(s0, off, 32); d0 += __shfl_xor(d0, off, 32);
    s1 += __shfl_xor(s1, off, 32); d1 += __shfl_xor(d1, off, 32);
    s2 += __shfl_xor(s2, off, 32); d2 += __shfl_xor(d2, off, 32);
    s3 += __shfl_xor(s3, off, 32); d3 += __shfl_xor(d3, off, 32);
  }
  if (c == 0) {
    ALf[n * 4 + hh] = s0 * LOG2E;     ARf[n * 4 + hh] = d0 * LOG2E;
    ALf[n * 4 + 2 + hh] = s1 * LOG2E; ARf[n * 4 + 2 + hh] = d1 * LOG2E;
    ALb[n * 4 + hh] = s2 * LOG2E;     ARb[n * 4 + hh] = d2 * LOG2E;
    ALb[n * 4 + 2 + hh] = s3 * LOG2E; ARb[n * 4 + 2 + hh] = d3 * LOG2E;
  }
}

// ---------------- fused softmax + aggregation: 4 edges/wave, 16 lanes/edge ----------------
// lane = sg*16 + l; sub-group sg handles edge (it*4 + sg); lane covers channels 8l..8l+7.
__global__ __launch_bounds__(256) void k_agg(
    const uint4* __restrict__ Xf, const uint4* __restrict__ Xb,
    const int* __restrict__ rpf, const int* __restrict__ adjf,
    const int* __restrict__ rpb, const int* __restrict__ adjb,
    const float* __restrict__ ALf, const float* __restrict__ ARf,
    const float* __restrict__ ALb, const float* __restrict__ ARb,
    const float* __restrict__ bf, const float* __restrict__ bb,
    unsigned* __restrict__ H16)
{
  const int dir = blockIdx.y;
  const int wave = threadIdx.x >> 6;
  const int n = blockIdx.x * 4 + wave;
  const uint4* X = dir ? Xb : Xf;
  const int* rp  = dir ? rpb : rpf;
  const int* adj = dir ? adjb : adjf;
  const float* AL = dir ? ALb : ALf;
  const float* AR = dir ? ARb : ARf;
  const float* bias = dir ? bb : bf;
  const int lane = threadIdx.x & 63;
  const int sg = lane >> 4;           // sub-group = which edge of the quad
  const unsigned l = (unsigned)(lane & 15);
  const unsigned h = l >> 2;          // head for channels 8l..8l+7
  const float arn = AR[((unsigned)n << 2) | h];
  const int beg = rp[n], end = rp[n + 1];
  const int cntE = end - beg;
  const int full = cntE >> 2;
  float a0 = 0.f, a1 = 0.f, a2 = 0.f, a3 = 0.f;
  float a4 = 0.f, a5 = 0.f, a6 = 0.f, a7 = 0.f, den = 0.f;
  const int* ap = adj + beg + sg;
#pragma unroll 4
  for (int it = 0; it < full; ++it, ap += 4) {
    int nb = *ap;
    float al = AL[((unsigned)nb << 2) | h];
    uint4 u = X[((unsigned)nb << 4) | l];
    float s = al + arn;
    float e = fmaxf(s, s * NEG_SLOPE);
    float w = fexp2(e);
    den += w;
    a0 = fmaf(w, bflo(u.x), a0); a1 = fmaf(w, bfhi(u.x), a1);
    a2 = fmaf(w, bflo(u.y), a2); a3 = fmaf(w, bfhi(u.y), a3);
    a4 = fmaf(w, bflo(u.z), a4); a5 = fmaf(w, bfhi(u.z), a5);
    a6 = fmaf(w, bflo(u.w), a6); a7 = fmaf(w, bfhi(u.w), a7);
  }
  const int rem = cntE & 3;
  if (rem) {
    int j = beg + 4 * full + sg;
    int jj = (sg < rem) ? j : beg;     // beg always valid (self loop)
    int nb = adj[jj];
    float al = AL[((unsigned)nb << 2) | h];
    uint4 u = X[((unsigned)nb << 4) | l];
    float s = al + arn;
    float e = fmaxf(s, s * NEG_SLOPE);
    float w = fexp2(e);
    w = (sg < rem) ? w : 0.f;
    den += w;
    a0 = fmaf(w, bflo(u.x), a0); a1 = fmaf(w, bfhi(u.x), a1);
    a2 = fmaf(w, bflo(u.y), a2); a3 = fmaf(w, bfhi(u.y), a3);
    a4 = fmaf(w, bflo(u.z), a4); a5 = fmaf(w, bfhi(u.z), a5);
    a6 = fmaf(w, bflo(u.w), a6); a7 = fmaf(w, bfhi(u.w), a7);
  }
  // reduce across the 4 sub-groups (xor 16, then 32)
#pragma unroll
  for (int off = 16; off <= 32; off <<= 1) {
    a0 += __shfl_xor(a0, off); a1 += __shfl_xor(a1, off);
    a2 += __shfl_xor(a2, off); a3 += __shfl_xor(a3, off);
    a4 += __shfl_xor(a4, off); a5 += __shfl_xor(a5, off);
    a6 += __shfl_xor(a6, off); a7 += __shfl_xor(a7, off);
    den += __shfl_xor(den, off);
  }
  if (lane < 16) {
    float inv = 1.f / (den + 1e-16f);
    float4 b0 = *(const float4*)(bias + 8 * l);
    float4 b1 = *(const float4*)(bias + 8 * l + 4);
    float v0 = a0 * inv + b0.x, v1 = a1 * inv + b0.y;
    float v2 = a2 * inv + b0.z, v3 = a3 * inv + b0.w;
    float v4 = a4 * inv + b1.x, v5 = a5 * inv + b1.y;
    float v6 = a6 * inv + b1.z, v7 = a7 * inv + b1.w;
    uint4 hw;
    hw.x = ((unsigned)f2bf(v1) << 16) | f2bf(v0);
    hw.y = ((unsigned)f2bf(v3) << 16) | f2bf(v2);
    hw.z = ((unsigned)f2bf(v5) << 16) | f2bf(v4);
    hw.w = ((unsigned)f2bf(v7) << 16) | f2bf(v6);
    *(uint4*)(H16 + (unsigned)n * 128u + (unsigned)dir * 64u + 4u * l) = hw;
  }
}

// ---------------- standalone fusion GEMM (mode 1) ----------------
__global__ __launch_bounds__(256) void k_mm2(
    const unsigned short* __restrict__ A, const unsigned short* __restrict__ Bt,
    float* __restrict__ Df,
    const float* __restrict__ bias, const float* __restrict__ gamma,
    const float* __restrict__ beta, const float* __restrict__ mean,
    const float* __restrict__ var)
{
  __shared__ __align__(16) unsigned short As[128 * LDA];
  __shared__ __align__(16) unsigned short Bs[128 * LDA];
  mm_body(A, N_NODES, Bt, nullptr, nullptr, Df, 1,
          bias, gamma, beta, mean, var,
          blockIdx.x * 128, blockIdx.y * 128, As, Bs);
}

// ---------------- launch ----------------

extern "C" void kernel_launch(void* const* d_in, const int* in_sizes, int n_in,
                              void* d_out, int out_size, void* d_ws, size_t ws_size,
                              hipStream_t stream) {
  const float* x    = (const float*)d_in[0];
  const int*   ei   = (const int*)d_in[1];
  const float* W_f  = (const float*)d_in[2];
  const float* asf  = (const float*)d_in[3];
  const float* adf  = (const float*)d_in[4];
  const float* b_f  = (const float*)d_in[5];
  const float* W_b  = (const float*)d_in[6];
  const float* asb  = (const float*)d_in[7];
  const float* adb  = (const float*)d_in[8];
  const float* b_b  = (const float*)d_in[9];
  const float* W_fu = (const float*)d_in[10];
  const float* b_fu = (const float*)d_in[11];
  const float* gam  = (const float*)d_in[12];
  const float* bet  = (const float*)d_in[13];
  const float* mean = (const float*)d_in[14];
  const float* var  = (const float*)d_in[15];
  float* out = (float*)d_out;

  char* base = (char*)d_ws;
  size_t off = 0;
  auto alloc = [&](size_t bytes) {
    void* p = base + off;
    off = (off + bytes + 255) & ~(size_t)255;
    return p;
  };
  // Xb16 (mm1 input) and H16 (agg output / mm2 input) live at disjoint times -> share
  unsigned short* Xb16 = (unsigned short*)alloc((size_t)N_NODES * 256 * 2);
  unsigned* H16        = (unsigned*)Xb16;
  unsigned short* Xf   = (unsigned short*)alloc((size_t)N_NODES * 128 * 2);
  unsigned short* Xb   = (unsigned short*)alloc((size_t)N_NODES * 128 * 2);
  unsigned short* Bt1  = (unsigned short*)alloc((size_t)256 * 256 * 2);
  unsigned short* Bt2  = (unsigned short*)alloc((size_t)256 * 256 * 2);
  float* ALf  = (float*)alloc((size_t)N_NODES * 4 * 4);
  float* ARf  = (float*)alloc((size_t)N_NODES * 4 * 4);
  float* ALb  = (float*)alloc((size_t)N_NODES * 4 * 4);
  float* ARb  = (float*)alloc((size_t)N_NODES * 4 * 4);
  int* rpf    = (int*)alloc((size_t)(N_NODES + 1) * 4);
  int* rpb    = (int*)alloc((size_t)(N_NODES + 1) * 4);
  int* adjf   = (int*)alloc((size_t)(N_EDGES + N_NODES) * 4);
  int* adjb   = (int*)alloc((size_t)(N_EDGES + N_NODES) * 4);
  int* blockhist = (int*)alloc((size_t)2 * NBUCK * NBLK * 4);
  int* blockoffs = (int*)alloc((size_t)2 * NBUCK * NBLK * 4);
  int* bucktotal = (int*)alloc((size_t)2 * NBUCK * 4);
  int* buckbase  = (int*)alloc((size_t)2 * (NBUCK + 1) * 4);
  unsigned* staging = (unsigned*)alloc((size_t)2 * N_EDGES * 4);
  (void)ws_size; (void)in_sizes; (void)n_in; (void)out_size;

  const int XB = (N_NODES * 64) / 256;            // 12500
  const int MB = (N_NODES + 127) / 128;           // 391

  k_setup<<<NBLK + 256 + XB, 256, 0, stream>>>(ei, blockhist, W_f, W_b, W_fu,
                                               Bt1, Bt2, x, Xb16);
  k_rowscan<<<2 * NBUCK, 256, 0, stream>>>(blockhist, blockoffs, bucktotal);
  k_buckscan<<<1, 256, 0, stream>>>(bucktotal, buckbase, rpf, rpb);
  // fused: edge staging (chain A) + projection GEMM (chain B)
  k_stage_mm<<<NBLK + MB * 2, 256, 0, stream>>>(ei, blockoffs, buckbase, staging,
                                                Xb16, Bt1, Xf, Xb);
  // fused: CSR binning (chain A) + attention scores (chain B)
  k_bin_scores<<<2 * NBUCK + N_NODES / 8, 512, 0, stream>>>(
      staging, buckbase, rpf, rpb, adjf, adjb,
      Xf, Xb, asf, adf, asb, adb, ALf, ARf, ALb, ARb);
  k_agg<<<dim3(N_NODES / 4, 2), 256, 0, stream>>>((const uint4*)Xf, (const uint4*)Xb,
                                                  rpf, adjf, rpb, adjb,
                                                  ALf, ARf, ALb, ARb, b_f, b_b, H16);
  k_mm2<<<dim3(MB, 2), 256, 0, stream>>>((const unsigned short*)H16, Bt2, out,
                                         b_fu, gam, bet, mean, var);
}